// Round 3
// baseline (15461.815 us; speedup 1.0000x reference)
//
#include <hip/hip_runtime.h>
#include <math.h>

#define BN_EPS 1e-5f

// ---------------------------------------------------------------------------
// Direct 3x3 conv, pad=1, stride template. Block = 16x16 threads, computes a
// 16x16 output tile for 4 consecutive output channels (COPB=4) of one batch.
// Input patch for the current input channel staged in LDS; weights are
// block-uniform (scalar-cached).
// ---------------------------------------------------------------------------
template<int STRIDE>
__global__ __launch_bounds__(256) void conv3x3_kernel(
    const float* __restrict__ in, const float* __restrict__ wgt,
    const float* __restrict__ bias, float* __restrict__ out,
    int B, int Cin, int H, int W, int Cout, int Ho, int Wo, int do_relu)
{
    constexpr int TH = 16, TW = 16;
    constexpr int PH = TH * STRIDE + 3 - STRIDE;   // 18 (s1) or 33 (s2)
    constexpr int PW = TW * STRIDE + 3 - STRIDE;
    constexpr int COPB = 4;
    __shared__ float patch[PH * PW];

    int cpg  = Cout / COPB;
    int bz   = blockIdx.z;
    int cog  = bz % cpg;
    int b    = bz / cpg;
    int co0  = cog * COPB;
    int tx   = threadIdx.x, ty = threadIdx.y;
    int ox0  = blockIdx.x * TW, oy0 = blockIdx.y * TH;
    int ox   = ox0 + tx, oy = oy0 + ty;
    int ix0  = ox0 * STRIDE - 1, iy0 = oy0 * STRIDE - 1;
    int tid  = ty * TW + tx;

    float acc[COPB];
    #pragma unroll
    for (int i = 0; i < COPB; i++) acc[i] = bias ? bias[co0 + i] : 0.f;

    const size_t HW = (size_t)H * W;
    for (int ci = 0; ci < Cin; ci++) {
        const float* ip = in + ((size_t)b * Cin + ci) * HW;
        for (int t = tid; t < PH * PW; t += 256) {
            int py = t / PW, px = t % PW;
            int gy = iy0 + py, gx = ix0 + px;
            float v = 0.f;
            if (gy >= 0 && gy < H && gx >= 0 && gx < W) v = ip[(size_t)gy * W + gx];
            patch[t] = v;
        }
        __syncthreads();
        float r[9];
        int ly = ty * STRIDE, lx = tx * STRIDE;
        #pragma unroll
        for (int ki = 0; ki < 3; ki++)
            #pragma unroll
            for (int kj = 0; kj < 3; kj++)
                r[ki * 3 + kj] = patch[(ly + ki) * PW + (lx + kj)];
        #pragma unroll
        for (int i = 0; i < COPB; i++) {
            const float* wp = wgt + ((size_t)(co0 + i) * Cin + ci) * 9;
            #pragma unroll
            for (int k = 0; k < 9; k++) acc[i] = fmaf(r[k], wp[k], acc[i]);
        }
        __syncthreads();
    }
    if (ox < Wo && oy < Ho) {
        #pragma unroll
        for (int i = 0; i < COPB; i++) {
            float v = acc[i];
            if (do_relu) v = fmaxf(v, 0.f);
            out[(((size_t)b * Cout + co0 + i) * Ho + oy) * Wo + ox] = v;
        }
    }
}

// ---------------------------------------------------------------------------
// FUSED offset-conv + deformable bilinear resample, with the reference's
// reshape semantics reproduced EXACTLY:
//   off.reshape(B*C, HW, 2): element [b*C+c, q, t] = flat[bc*2HW + 2q + t]
//   => conv channel ch = 2c + (2q+t)/HW, conv pixel p = (2q+t) mod HW.
//   Inverse: conv pixel pair (p even, p+1) of channel 2c+half supplies
//   (oi, oj) for output pixel q = half*HW/2 + p/2; the bilinear grid is
//   anchored at the OUTPUT pixel (q/W, q%W).
// Each block: 16x16 tile of CONV pixels for channel pair (2c, 2c+1) of one
// (b, c); conv results staged to LDS, epilogue remaps pairs to outputs.
// Grid: (ceil(W/16), ceil(H/16), B*C).
// ---------------------------------------------------------------------------
__global__ __launch_bounds__(256) void offdeform_kernel(
    const float* __restrict__ x, const float* __restrict__ woff,
    float* __restrict__ out, int B, int C, int H, int W)
{
    __shared__ float patch[18 * 18];
    __shared__ float sconv0[256];   // conv channel 2c   over the tile
    __shared__ float sconv1[256];   // conv channel 2c+1 over the tile
    int z  = blockIdx.z;
    int c  = z % C, b = z / C;
    int tx = threadIdx.x, ty = threadIdx.y;
    int pj0 = blockIdx.x * 16, pi0 = blockIdx.y * 16;   // conv-pixel tile origin
    int ix0 = pj0 - 1, iy0 = pi0 - 1;
    int tid = ty * 16 + tx;

    const int HW = H * W;
    const float* xb = x + (size_t)b * C * HW;

    float a0 = 0.f, a1 = 0.f;   // conv accum: channels 2c, 2c+1 at (pi0+ty, pj0+tx)
    for (int ci = 0; ci < C; ci++) {
        const float* ip = xb + (size_t)ci * HW;
        for (int t = tid; t < 324; t += 256) {
            int py = t / 18, px = t % 18;
            int gy = iy0 + py, gx = ix0 + px;
            float v = 0.f;
            if (gy >= 0 && gy < H && gx >= 0 && gx < W) v = ip[(size_t)gy * W + gx];
            patch[t] = v;
        }
        __syncthreads();
        float r[9];
        #pragma unroll
        for (int ki = 0; ki < 3; ki++)
            #pragma unroll
            for (int kj = 0; kj < 3; kj++)
                r[ki * 3 + kj] = patch[(ty + ki) * 18 + (tx + kj)];
        const float* w0 = woff + ((size_t)(2 * c)     * C + ci) * 9;
        const float* w1 = woff + ((size_t)(2 * c + 1) * C + ci) * 9;
        #pragma unroll
        for (int k = 0; k < 9; k++) {
            a0 = fmaf(r[k], w0[k], a0);
            a1 = fmaf(r[k], w1[k], a1);
        }
        __syncthreads();
    }

    sconv0[tid] = a0;
    sconv1[tid] = a1;
    __syncthreads();

    // Epilogue: 256 outputs per block = 2 halves x 16 rows x 8 pixel-pairs.
    int half = tid >> 7;          // 0: channel 2c (q < HW/2), 1: channel 2c+1
    int w2   = tid & 127;
    int ry   = w2 >> 3, rx = w2 & 7;
    int prow = pi0 + ry;
    int pcol = pj0 + 2 * rx;      // even (pj0 is 16-aligned)
    if (prow < H && pcol < W) {
        const float* sc = half ? sconv1 : sconv0;
        float oi = sc[ry * 16 + 2 * rx];
        float oj = sc[ry * 16 + 2 * rx + 1];
        int p0 = prow * W + pcol;             // even
        int q  = half * (HW >> 1) + (p0 >> 1);
        int qi = q / W, qj = q % W;
        float ci_ = fminf(fmaxf(oi + (float)qi, 0.f), (float)(H - 1));
        float cj_ = fminf(fmaxf(oj + (float)qj, 0.f), (float)(W - 1));
        float i0f = floorf(ci_), j0f = floorf(cj_);
        int i0 = (int)i0f, i1 = (int)ceilf(ci_);
        int j0 = (int)j0f, j1 = (int)ceilf(cj_);
        const float* xp = xb + (size_t)c * HW;
        float v00 = xp[i0 * W + j0];
        float v10 = xp[i1 * W + j0];
        float v01 = xp[i0 * W + j1];
        float v11 = xp[i1 * W + j1];
        float di = ci_ - i0f, dj = cj_ - j0f;
        float top = v00 + di * (v10 - v00);
        float bot = v01 + di * (v11 - v01);
        out[((size_t)b * C + c) * HW + q] = top + dj * (bot - top);
    }
}

// ---------------------------------------------------------------------------
// BN batch statistics: per-channel sum and sum-of-squares (over N,H,W).
// ---------------------------------------------------------------------------
__global__ __launch_bounds__(256) void bn_stats_kernel(
    const float* __restrict__ x, float* __restrict__ stats,
    int B, int C, int HW)
{
    int c = blockIdx.x;
    long long cnt = (long long)B * HW;
    long long step = (long long)gridDim.y * blockDim.x;
    float s = 0.f, s2 = 0.f;
    for (long long t = (long long)blockIdx.y * blockDim.x + threadIdx.x; t < cnt; t += step) {
        int b  = (int)(t / HW);
        int sp = (int)(t % HW);
        float v = x[((size_t)b * C + c) * (size_t)HW + sp];
        s += v; s2 += v * v;
    }
    for (int off = 32; off; off >>= 1) {
        s  += __shfl_down(s, off);
        s2 += __shfl_down(s2, off);
    }
    __shared__ float ls[4], ls2[4];
    int wave = threadIdx.x >> 6, lane = threadIdx.x & 63;
    if (lane == 0) { ls[wave] = s; ls2[wave] = s2; }
    __syncthreads();
    if (threadIdx.x == 0) {
        float ts = 0.f, ts2 = 0.f;
        for (int i = 0; i < 4; i++) { ts += ls[i]; ts2 += ls2[i]; }
        atomicAdd(&stats[c], ts);
        atomicAdd(&stats[C + c], ts2);
    }
}

// ---------------------------------------------------------------------------
// BN apply (in-place): y = (x - m) * rsqrt(v + eps) * g + be
// ---------------------------------------------------------------------------
__global__ __launch_bounds__(256) void bn_apply_kernel(
    float* __restrict__ x, const float* __restrict__ stats,
    const float* __restrict__ g, const float* __restrict__ be,
    int B, int C, int HW)
{
    size_t total = (size_t)B * C * HW;
    float inv_cnt = 1.f / ((float)B * (float)HW);
    size_t i = (size_t)blockIdx.x * blockDim.x + threadIdx.x;
    if (i >= total) return;
    int c = (int)((i / (size_t)HW) % C);
    float m  = stats[c] * inv_cnt;
    float v  = stats[C + c] * inv_cnt - m * m;
    float sc = g[c] / sqrtf(v + BN_EPS);
    float sh = be[c] - m * sc;
    x[i] = x[i] * sc + sh;
}

// ---------------------------------------------------------------------------
__global__ void zero_kernel(float* __restrict__ p, int n)
{
    int i = blockIdx.x * blockDim.x + threadIdx.x;
    if (i < n) p[i] = 0.f;
}

// ---------------------------------------------------------------------------
// Global average pool: one block per (b,c), mean over HW.
// ---------------------------------------------------------------------------
__global__ __launch_bounds__(256) void pool_kernel(
    const float* __restrict__ x, float* __restrict__ out, int HW)
{
    int bc = blockIdx.x;
    const float* xp = x + (size_t)bc * HW;
    float s = 0.f;
    for (int i = threadIdx.x; i < HW; i += blockDim.x) s += xp[i];
    for (int off = 32; off; off >>= 1) s += __shfl_down(s, off);
    __shared__ float ls[4];
    int wave = threadIdx.x >> 6, lane = threadIdx.x & 63;
    if (lane == 0) ls[wave] = s;
    __syncthreads();
    if (threadIdx.x == 0) {
        float t = 0.f;
        for (int i = 0; i < 4; i++) t += ls[i];
        out[bc] = t / (float)HW;
    }
}

// ---------------------------------------------------------------------------
// FC (128 -> 10) + softmax per batch row. Block = 128 threads, grid = B.
// ---------------------------------------------------------------------------
__global__ __launch_bounds__(128) void fc_softmax_kernel(
    const float* __restrict__ pool, const float* __restrict__ wfc,
    const float* __restrict__ bfc, float* __restrict__ out)
{
    int b = blockIdx.x;
    __shared__ float row[128];
    __shared__ float logits[10];
    int tid = threadIdx.x;
    row[tid] = pool[b * 128 + tid];
    __syncthreads();
    if (tid < 10) {
        float s = bfc[tid];
        for (int k = 0; k < 128; k++) s = fmaf(row[k], wfc[tid * 128 + k], s);
        logits[tid] = s;
    }
    __syncthreads();
    if (tid < 10) {
        float mx = logits[0];
        for (int i = 1; i < 10; i++) mx = fmaxf(mx, logits[i]);
        float sum = 0.f;
        for (int i = 0; i < 10; i++) sum += expf(logits[i] - mx);
        out[b * 10 + tid] = expf(logits[tid] - mx) / sum;
    }
}

// ---------------------------------------------------------------------------
extern "C" void kernel_launch(void* const* d_in, const int* in_sizes, int n_in,
                              void* d_out, int out_size, void* d_ws, size_t ws_size,
                              hipStream_t stream)
{
    const float* x      = (const float*)d_in[0];
    const float* w11    = (const float*)d_in[1];
    const float* b11    = (const float*)d_in[2];
    const float* g11    = (const float*)d_in[3];
    const float* be11   = (const float*)d_in[4];
    const float* woff12 = (const float*)d_in[5];
    const float* w12    = (const float*)d_in[6];
    const float* b12    = (const float*)d_in[7];
    const float* g12    = (const float*)d_in[8];
    const float* be12   = (const float*)d_in[9];
    const float* woff21 = (const float*)d_in[10];
    const float* w21    = (const float*)d_in[11];
    const float* b21    = (const float*)d_in[12];
    const float* g21    = (const float*)d_in[13];
    const float* be21   = (const float*)d_in[14];
    const float* woff22 = (const float*)d_in[15];
    const float* w22    = (const float*)d_in[16];
    const float* b22    = (const float*)d_in[17];
    const float* g22    = (const float*)d_in[18];
    const float* be22   = (const float*)d_in[19];
    const float* wfc    = (const float*)d_in[20];
    const float* bfc    = (const float*)d_in[21];
    float* out = (float*)d_out;

    // Arena (floats): two ping-pong activation buffers of SZ_B = 25,690,112
    // floats (= 64*32*112*112 = 64*128*56*56) + stats(512) + pool(8192).
    // Total = 205,555,712 bytes.
    float* ws    = (float*)d_ws;
    const size_t SZ_B = 25690112;
    float* Bbuf  = ws;
    float* Cbuf  = Bbuf + SZ_B;
    float* stats = Cbuf + SZ_B;
    float* poolb = stats + 512;

    dim3 blk2d(16, 16);
    const int B = 64;

    // ---- Layer 1.1: conv(1->32, s1) + relu -> Bbuf; BN in-place ----
    conv3x3_kernel<1><<<dim3(7, 7, B * (32 / 4)), blk2d, 0, stream>>>(
        x, w11, b11, Bbuf, B, 1, 112, 112, 32, 112, 112, 1);
    zero_kernel<<<2, 256, 0, stream>>>(stats, 512);
    bn_stats_kernel<<<dim3(32, 64), 256, 0, stream>>>(Bbuf, stats, B, 32, 12544);
    {
        size_t total = (size_t)B * 32 * 12544;
        bn_apply_kernel<<<(total + 255) / 256, 256, 0, stream>>>(
            Bbuf, stats, g11, be11, B, 32, 12544);
    }

    // ---- deform12 (fused offconv 32->64 + resample): Bbuf -> Cbuf ----
    offdeform_kernel<<<dim3(7, 7, B * 32), blk2d, 0, stream>>>(
        Bbuf, woff12, Cbuf, B, 32, 112, 112);

    // ---- Layer 1.2: conv(32->64, s2) + relu -> Bbuf; BN in-place ----
    conv3x3_kernel<2><<<dim3(4, 4, B * (64 / 4)), blk2d, 0, stream>>>(
        Cbuf, w12, b12, Bbuf, B, 32, 112, 112, 64, 56, 56, 1);
    zero_kernel<<<2, 256, 0, stream>>>(stats, 512);
    bn_stats_kernel<<<dim3(64, 64), 256, 0, stream>>>(Bbuf, stats, B, 64, 3136);
    {
        size_t total = (size_t)B * 64 * 3136;
        bn_apply_kernel<<<(total + 255) / 256, 256, 0, stream>>>(
            Bbuf, stats, g12, be12, B, 64, 3136);
    }

    // ---- deform21 (fused offconv 64->128 + resample): Bbuf -> Cbuf ----
    offdeform_kernel<<<dim3(4, 4, B * 64), blk2d, 0, stream>>>(
        Bbuf, woff21, Cbuf, B, 64, 56, 56);

    // ---- Layer 2.1: conv(64->128, s1) + relu -> Bbuf; BN in-place ----
    conv3x3_kernel<1><<<dim3(4, 4, B * (128 / 4)), blk2d, 0, stream>>>(
        Cbuf, w21, b21, Bbuf, B, 64, 56, 56, 128, 56, 56, 1);
    zero_kernel<<<2, 256, 0, stream>>>(stats, 512);
    bn_stats_kernel<<<dim3(128, 64), 256, 0, stream>>>(Bbuf, stats, B, 128, 3136);
    {
        size_t total = (size_t)B * 128 * 3136;
        bn_apply_kernel<<<(total + 255) / 256, 256, 0, stream>>>(
            Bbuf, stats, g21, be21, B, 128, 3136);
    }

    // ---- deform22 (fused offconv 128->256 + resample): Bbuf -> Cbuf ----
    offdeform_kernel<<<dim3(4, 4, B * 128), blk2d, 0, stream>>>(
        Bbuf, woff22, Cbuf, B, 128, 56, 56);

    // ---- Layer 2.2: conv(128->128, s2) + relu -> Bbuf; BN in-place ----
    conv3x3_kernel<2><<<dim3(2, 2, B * (128 / 4)), blk2d, 0, stream>>>(
        Cbuf, w22, b22, Bbuf, B, 128, 56, 56, 128, 28, 28, 1);
    zero_kernel<<<2, 256, 0, stream>>>(stats, 512);
    bn_stats_kernel<<<dim3(128, 64), 256, 0, stream>>>(Bbuf, stats, B, 128, 784);
    {
        size_t total = (size_t)B * 128 * 784;
        bn_apply_kernel<<<(total + 255) / 256, 256, 0, stream>>>(
            Bbuf, stats, g22, be22, B, 128, 784);
    }

    // ---- Pool + FC + softmax ----
    pool_kernel<<<B * 128, 256, 0, stream>>>(Bbuf, poolb, 784);
    fc_softmax_kernel<<<B, 128, 0, stream>>>(poolb, wfc, bfc, out);
}

// Round 4
// 7733.656 us; speedup vs baseline: 1.9993x; 1.9993x over previous
//
#include <hip/hip_runtime.h>
#include <math.h>

#define BN_EPS 1e-5f

// ---------------------------------------------------------------------------
// Direct 3x3 conv, pad=1, stride template. Block = 16x16 threads, computes a
// 16x16 output tile for COPB=8 consecutive output channels of one batch.
// Input patch for the current input channel staged in LDS; weights are
// block-uniform (scalar-cached). 9 LDS reads feed 72 FMAs per ci.
// ---------------------------------------------------------------------------
template<int STRIDE>
__global__ __launch_bounds__(256) void conv3x3_kernel(
    const float* __restrict__ in, const float* __restrict__ wgt,
    const float* __restrict__ bias, float* __restrict__ out,
    int B, int Cin, int H, int W, int Cout, int Ho, int Wo, int do_relu)
{
    constexpr int TH = 16, TW = 16;
    constexpr int PH = TH * STRIDE + 3 - STRIDE;   // 18 (s1) or 33 (s2)
    constexpr int PW = TW * STRIDE + 3 - STRIDE;
    constexpr int COPB = 8;
    __shared__ float patch[PH * PW];

    int cpg  = Cout / COPB;
    int bz   = blockIdx.z;
    int cog  = bz % cpg;
    int b    = bz / cpg;
    int co0  = cog * COPB;
    int tx   = threadIdx.x, ty = threadIdx.y;
    int ox0  = blockIdx.x * TW, oy0 = blockIdx.y * TH;
    int ox   = ox0 + tx, oy = oy0 + ty;
    int ix0  = ox0 * STRIDE - 1, iy0 = oy0 * STRIDE - 1;
    int tid  = ty * TW + tx;

    float acc[COPB];
    #pragma unroll
    for (int i = 0; i < COPB; i++) acc[i] = bias ? bias[co0 + i] : 0.f;

    const size_t HW = (size_t)H * W;
    for (int ci = 0; ci < Cin; ci++) {
        const float* ip = in + ((size_t)b * Cin + ci) * HW;
        for (int t = tid; t < PH * PW; t += 256) {
            int py = t / PW, px = t % PW;
            int gy = iy0 + py, gx = ix0 + px;
            float v = 0.f;
            if (gy >= 0 && gy < H && gx >= 0 && gx < W) v = ip[(size_t)gy * W + gx];
            patch[t] = v;
        }
        __syncthreads();
        float r[9];
        int ly = ty * STRIDE, lx = tx * STRIDE;
        #pragma unroll
        for (int ki = 0; ki < 3; ki++)
            #pragma unroll
            for (int kj = 0; kj < 3; kj++)
                r[ki * 3 + kj] = patch[(ly + ki) * PW + (lx + kj)];
        const float* wb = wgt + ((size_t)co0 * Cin + ci) * 9;
        #pragma unroll
        for (int i = 0; i < COPB; i++) {
            const float* wp = wb + (size_t)i * Cin * 9;
            #pragma unroll
            for (int k = 0; k < 9; k++) acc[i] = fmaf(r[k], wp[k], acc[i]);
        }
        __syncthreads();
    }
    if (ox < Wo && oy < Ho) {
        #pragma unroll
        for (int i = 0; i < COPB; i++) {
            float v = acc[i];
            if (do_relu) v = fmaxf(v, 0.f);
            out[(((size_t)b * Cout + co0 + i) * Ho + oy) * Wo + ox] = v;
        }
    }
}

// ---------------------------------------------------------------------------
// FUSED offset-conv + deformable bilinear resample, reference reshape
// semantics reproduced EXACTLY (see round-2 derivation):
//   conv pixel pair (p even, p+1) of conv channel 2c+half supplies (oi, oj)
//   for output pixel q = half*HW/2 + p/2; bilinear grid anchored at the
//   OUTPUT pixel (q/W, q%W).
// Each block: 16x16 tile of CONV pixels for CP=4 channel pairs (8 conv
// channels) of one (b, channel-group); conv results staged to LDS, epilogue
// remaps pairs to outputs. Grid: (W/16, H/16, B*C/CP).
// ---------------------------------------------------------------------------
template<int CP>
__global__ __launch_bounds__(256) void offdeform_kernel(
    const float* __restrict__ x, const float* __restrict__ woff,
    float* __restrict__ out, int B, int C, int H, int W)
{
    __shared__ float patch[18 * 18];
    __shared__ float sconv[2 * CP][256];   // conv channels 2c0 .. 2c0+2CP-1
    int groups = C / CP;
    int z  = blockIdx.z;
    int g  = z % groups, b = z / groups;
    int c0 = g * CP;                        // image channels c0 .. c0+CP-1
    int tx = threadIdx.x, ty = threadIdx.y;
    int pj0 = blockIdx.x * 16, pi0 = blockIdx.y * 16;   // conv-pixel tile origin
    int ix0 = pj0 - 1, iy0 = pi0 - 1;
    int tid = ty * 16 + tx;

    const int HW = H * W;
    const float* xb = x + (size_t)b * C * HW;

    float acc[2 * CP];
    #pragma unroll
    for (int i = 0; i < 2 * CP; i++) acc[i] = 0.f;

    for (int ci = 0; ci < C; ci++) {
        const float* ip = xb + (size_t)ci * HW;
        for (int t = tid; t < 324; t += 256) {
            int py = t / 18, px = t % 18;
            int gy = iy0 + py, gx = ix0 + px;
            float v = 0.f;
            if (gy >= 0 && gy < H && gx >= 0 && gx < W) v = ip[(size_t)gy * W + gx];
            patch[t] = v;
        }
        __syncthreads();
        float r[9];
        #pragma unroll
        for (int ki = 0; ki < 3; ki++)
            #pragma unroll
            for (int kj = 0; kj < 3; kj++)
                r[ki * 3 + kj] = patch[(ty + ki) * 18 + (tx + kj)];
        const float* wb = woff + ((size_t)(2 * c0) * C + ci) * 9;
        #pragma unroll
        for (int ch = 0; ch < 2 * CP; ch++) {
            const float* wp = wb + (size_t)ch * C * 9;
            #pragma unroll
            for (int k = 0; k < 9; k++) acc[ch] = fmaf(r[k], wp[k], acc[ch]);
        }
        __syncthreads();
    }

    #pragma unroll
    for (int ch = 0; ch < 2 * CP; ch++) sconv[ch][tid] = acc[ch];
    __syncthreads();

    // Epilogue: per pair, 256 outputs = 2 halves x 16 rows x 8 pixel-pairs.
    int half = tid >> 7;          // 0: conv channel 2c (q < HW/2), 1: 2c+1
    int w2   = tid & 127;
    int ry   = w2 >> 3, rx = w2 & 7;
    int prow = pi0 + ry;
    int pcol = pj0 + 2 * rx;      // even (pj0 is 16-aligned)
    if (prow < H && pcol < W) {
        int p0 = prow * W + pcol;             // even
        int q  = half * (HW >> 1) + (p0 >> 1);
        int qi = q / W, qj = q % W;
        #pragma unroll
        for (int pp = 0; pp < CP; pp++) {
            int c = c0 + pp;
            float oi = sconv[2 * pp + half][ry * 16 + 2 * rx];
            float oj = sconv[2 * pp + half][ry * 16 + 2 * rx + 1];
            float ci_ = fminf(fmaxf(oi + (float)qi, 0.f), (float)(H - 1));
            float cj_ = fminf(fmaxf(oj + (float)qj, 0.f), (float)(W - 1));
            float i0f = floorf(ci_), j0f = floorf(cj_);
            int i0 = (int)i0f, i1 = (int)ceilf(ci_);
            int j0 = (int)j0f, j1 = (int)ceilf(cj_);
            const float* xp = xb + (size_t)c * HW;
            float v00 = xp[i0 * W + j0];
            float v10 = xp[i1 * W + j0];
            float v01 = xp[i0 * W + j1];
            float v11 = xp[i1 * W + j1];
            float di = ci_ - i0f, dj = cj_ - j0f;
            float top = v00 + di * (v10 - v00);
            float bot = v01 + di * (v11 - v01);
            out[((size_t)b * C + c) * HW + q] = top + dj * (bot - top);
        }
    }
}

// ---------------------------------------------------------------------------
// BN batch statistics: per-channel sum and sum-of-squares (over N,H,W).
// ---------------------------------------------------------------------------
__global__ __launch_bounds__(256) void bn_stats_kernel(
    const float* __restrict__ x, float* __restrict__ stats,
    int B, int C, int HW)
{
    int c = blockIdx.x;
    long long cnt = (long long)B * HW;
    long long step = (long long)gridDim.y * blockDim.x;
    float s = 0.f, s2 = 0.f;
    for (long long t = (long long)blockIdx.y * blockDim.x + threadIdx.x; t < cnt; t += step) {
        int b  = (int)(t / HW);
        int sp = (int)(t % HW);
        float v = x[((size_t)b * C + c) * (size_t)HW + sp];
        s += v; s2 += v * v;
    }
    for (int off = 32; off; off >>= 1) {
        s  += __shfl_down(s, off);
        s2 += __shfl_down(s2, off);
    }
    __shared__ float ls[4], ls2[4];
    int wave = threadIdx.x >> 6, lane = threadIdx.x & 63;
    if (lane == 0) { ls[wave] = s; ls2[wave] = s2; }
    __syncthreads();
    if (threadIdx.x == 0) {
        float ts = 0.f, ts2 = 0.f;
        for (int i = 0; i < 4; i++) { ts += ls[i]; ts2 += ls2[i]; }
        atomicAdd(&stats[c], ts);
        atomicAdd(&stats[C + c], ts2);
    }
}

// ---------------------------------------------------------------------------
// BN apply (in-place): y = (x - m) * rsqrt(v + eps) * g + be
// ---------------------------------------------------------------------------
__global__ __launch_bounds__(256) void bn_apply_kernel(
    float* __restrict__ x, const float* __restrict__ stats,
    const float* __restrict__ g, const float* __restrict__ be,
    int B, int C, int HW)
{
    size_t total = (size_t)B * C * HW;
    float inv_cnt = 1.f / ((float)B * (float)HW);
    size_t i = (size_t)blockIdx.x * blockDim.x + threadIdx.x;
    if (i >= total) return;
    int c = (int)((i / (size_t)HW) % C);
    float m  = stats[c] * inv_cnt;
    float v  = stats[C + c] * inv_cnt - m * m;
    float sc = g[c] / sqrtf(v + BN_EPS);
    float sh = be[c] - m * sc;
    x[i] = x[i] * sc + sh;
}

// ---------------------------------------------------------------------------
__global__ void zero_kernel(float* __restrict__ p, int n)
{
    int i = blockIdx.x * blockDim.x + threadIdx.x;
    if (i < n) p[i] = 0.f;
}

// ---------------------------------------------------------------------------
// Global average pool: one block per (b,c), mean over HW.
// ---------------------------------------------------------------------------
__global__ __launch_bounds__(256) void pool_kernel(
    const float* __restrict__ x, float* __restrict__ out, int HW)
{
    int bc = blockIdx.x;
    const float* xp = x + (size_t)bc * HW;
    float s = 0.f;
    for (int i = threadIdx.x; i < HW; i += blockDim.x) s += xp[i];
    for (int off = 32; off; off >>= 1) s += __shfl_down(s, off);
    __shared__ float ls[4];
    int wave = threadIdx.x >> 6, lane = threadIdx.x & 63;
    if (lane == 0) ls[wave] = s;
    __syncthreads();
    if (threadIdx.x == 0) {
        float t = 0.f;
        for (int i = 0; i < 4; i++) t += ls[i];
        out[bc] = t / (float)HW;
    }
}

// ---------------------------------------------------------------------------
// FC (128 -> 10) + softmax per batch row. Block = 128 threads, grid = B.
// ---------------------------------------------------------------------------
__global__ __launch_bounds__(128) void fc_softmax_kernel(
    const float* __restrict__ pool, const float* __restrict__ wfc,
    const float* __restrict__ bfc, float* __restrict__ out)
{
    int b = blockIdx.x;
    __shared__ float row[128];
    __shared__ float logits[10];
    int tid = threadIdx.x;
    row[tid] = pool[b * 128 + tid];
    __syncthreads();
    if (tid < 10) {
        float s = bfc[tid];
        for (int k = 0; k < 128; k++) s = fmaf(row[k], wfc[tid * 128 + k], s);
        logits[tid] = s;
    }
    __syncthreads();
    if (tid < 10) {
        float mx = logits[0];
        for (int i = 1; i < 10; i++) mx = fmaxf(mx, logits[i]);
        float sum = 0.f;
        for (int i = 0; i < 10; i++) sum += expf(logits[i] - mx);
        out[b * 10 + tid] = expf(logits[tid] - mx) / sum;
    }
}

// ---------------------------------------------------------------------------
extern "C" void kernel_launch(void* const* d_in, const int* in_sizes, int n_in,
                              void* d_out, int out_size, void* d_ws, size_t ws_size,
                              hipStream_t stream)
{
    const float* x      = (const float*)d_in[0];
    const float* w11    = (const float*)d_in[1];
    const float* b11    = (const float*)d_in[2];
    const float* g11    = (const float*)d_in[3];
    const float* be11   = (const float*)d_in[4];
    const float* woff12 = (const float*)d_in[5];
    const float* w12    = (const float*)d_in[6];
    const float* b12    = (const float*)d_in[7];
    const float* g12    = (const float*)d_in[8];
    const float* be12   = (const float*)d_in[9];
    const float* woff21 = (const float*)d_in[10];
    const float* w21    = (const float*)d_in[11];
    const float* b21    = (const float*)d_in[12];
    const float* g21    = (const float*)d_in[13];
    const float* be21   = (const float*)d_in[14];
    const float* woff22 = (const float*)d_in[15];
    const float* w22    = (const float*)d_in[16];
    const float* b22    = (const float*)d_in[17];
    const float* g22    = (const float*)d_in[18];
    const float* be22   = (const float*)d_in[19];
    const float* wfc    = (const float*)d_in[20];
    const float* bfc    = (const float*)d_in[21];
    float* out = (float*)d_out;

    // Arena (floats): two ping-pong activation buffers of SZ_B = 25,690,112
    // floats (= 64*32*112*112 = 64*128*56*56) + stats(512) + pool(8192).
    // Total = 205,555,712 bytes.
    float* ws    = (float*)d_ws;
    const size_t SZ_B = 25690112;
    float* Bbuf  = ws;
    float* Cbuf  = Bbuf + SZ_B;
    float* stats = Cbuf + SZ_B;
    float* poolb = stats + 512;

    dim3 blk2d(16, 16);
    const int B = 64;

    // ---- Layer 1.1: conv(1->32, s1) + relu -> Bbuf; BN in-place ----
    conv3x3_kernel<1><<<dim3(7, 7, B * (32 / 8)), blk2d, 0, stream>>>(
        x, w11, b11, Bbuf, B, 1, 112, 112, 32, 112, 112, 1);
    zero_kernel<<<2, 256, 0, stream>>>(stats, 512);
    bn_stats_kernel<<<dim3(32, 64), 256, 0, stream>>>(Bbuf, stats, B, 32, 12544);
    {
        size_t total = (size_t)B * 32 * 12544;
        bn_apply_kernel<<<(total + 255) / 256, 256, 0, stream>>>(
            Bbuf, stats, g11, be11, B, 32, 12544);
    }

    // ---- deform12 (fused offconv 32->64 + resample): Bbuf -> Cbuf ----
    offdeform_kernel<4><<<dim3(7, 7, B * (32 / 4)), blk2d, 0, stream>>>(
        Bbuf, woff12, Cbuf, B, 32, 112, 112);

    // ---- Layer 1.2: conv(32->64, s2) + relu -> Bbuf; BN in-place ----
    conv3x3_kernel<2><<<dim3(4, 4, B * (64 / 8)), blk2d, 0, stream>>>(
        Cbuf, w12, b12, Bbuf, B, 32, 112, 112, 64, 56, 56, 1);
    zero_kernel<<<2, 256, 0, stream>>>(stats, 512);
    bn_stats_kernel<<<dim3(64, 64), 256, 0, stream>>>(Bbuf, stats, B, 64, 3136);
    {
        size_t total = (size_t)B * 64 * 3136;
        bn_apply_kernel<<<(total + 255) / 256, 256, 0, stream>>>(
            Bbuf, stats, g12, be12, B, 64, 3136);
    }

    // ---- deform21 (fused offconv 64->128 + resample): Bbuf -> Cbuf ----
    offdeform_kernel<4><<<dim3(4, 4, B * (64 / 4)), blk2d, 0, stream>>>(
        Bbuf, woff21, Cbuf, B, 64, 56, 56);

    // ---- Layer 2.1: conv(64->128, s1) + relu -> Bbuf; BN in-place ----
    conv3x3_kernel<1><<<dim3(4, 4, B * (128 / 8)), blk2d, 0, stream>>>(
        Cbuf, w21, b21, Bbuf, B, 64, 56, 56, 128, 56, 56, 1);
    zero_kernel<<<2, 256, 0, stream>>>(stats, 512);
    bn_stats_kernel<<<dim3(128, 64), 256, 0, stream>>>(Bbuf, stats, B, 128, 3136);
    {
        size_t total = (size_t)B * 128 * 3136;
        bn_apply_kernel<<<(total + 255) / 256, 256, 0, stream>>>(
            Bbuf, stats, g21, be21, B, 128, 3136);
    }

    // ---- deform22 (fused offconv 128->256 + resample): Bbuf -> Cbuf ----
    offdeform_kernel<4><<<dim3(4, 4, B * (128 / 4)), blk2d, 0, stream>>>(
        Bbuf, woff22, Cbuf, B, 128, 56, 56);

    // ---- Layer 2.2: conv(128->128, s2) + relu -> Bbuf; BN in-place ----
    conv3x3_kernel<2><<<dim3(2, 2, B * (128 / 8)), blk2d, 0, stream>>>(
        Cbuf, w22, b22, Bbuf, B, 128, 56, 56, 128, 28, 28, 1);
    zero_kernel<<<2, 256, 0, stream>>>(stats, 512);
    bn_stats_kernel<<<dim3(128, 64), 256, 0, stream>>>(Bbuf, stats, B, 128, 784);
    {
        size_t total = (size_t)B * 128 * 784;
        bn_apply_kernel<<<(total + 255) / 256, 256, 0, stream>>>(
            Bbuf, stats, g22, be22, B, 128, 784);
    }

    // ---- Pool + FC + softmax ----
    pool_kernel<<<B * 128, 256, 0, stream>>>(Bbuf, poolb, 784);
    fc_softmax_kernel<<<B, 128, 0, stream>>>(poolb, wfc, bfc, out);
}

// Round 5
// 5557.264 us; speedup vs baseline: 2.7823x; 1.3916x over previous
//
#include <hip/hip_runtime.h>
#include <math.h>

#define BN_EPS 1e-5f

// ---------------------------------------------------------------------------
// Direct 3x3 conv, pad=1. Block = 256 threads; 196 active threads (14x14)
// each compute a 2x2 output-pixel quad for COPB=8 consecutive output
// channels => 28x28 output tile per block (exact for 112/56/28 outputs).
// Per input channel: stage patch to LDS, read (S+3)^2 window per thread,
// 288 FMAs per thread. Weights are block-uniform (scalar loads).
// ---------------------------------------------------------------------------
template<int STRIDE>
__global__ __launch_bounds__(256) void conv3x3_kernel(
    const float* __restrict__ in, const float* __restrict__ wgt,
    const float* __restrict__ bias, float* __restrict__ out,
    int B, int Cin, int H, int W, int Cout, int Ho, int Wo, int do_relu)
{
    constexpr int TILE = 28;
    constexpr int PR   = (TILE - 1) * STRIDE + 3;           // 30 (s1) / 57 (s2)
    constexpr int PADW = (STRIDE == 1) ? 32 : 60;           // 16B-aligned rows
    constexpr int COPB = 8;
    constexpr int RW   = STRIDE + 3;                        // 4 (s1) / 5 (s2)
    __shared__ float patch[PR * PADW];

    int cpg  = Cout / COPB;
    int bz   = blockIdx.z;
    int cog  = bz % cpg;
    int b    = bz / cpg;
    int co0  = cog * COPB;
    int tid  = threadIdx.x;
    int oy0  = blockIdx.y * TILE, ox0 = blockIdx.x * TILE;
    int iy0  = oy0 * STRIDE - 1,  ix0 = ox0 * STRIDE - 1;

    bool active = tid < 196;
    int ty = tid / 14, tx = tid % 14;
    int py = oy0 + 2 * ty, px = ox0 + 2 * tx;   // output quad origin

    float acc[COPB][4];
    #pragma unroll
    for (int i = 0; i < COPB; i++) {
        float bv = bias ? bias[co0 + i] : 0.f;
        #pragma unroll
        for (int j = 0; j < 4; j++) acc[i][j] = bv;
    }

    const size_t HW = (size_t)H * W;
    for (int ci = 0; ci < Cin; ci++) {
        const float* ip = in + ((size_t)b * Cin + ci) * HW;
        for (int t = tid; t < PR * PADW; t += 256) {
            int sy = t / PADW, sx = t % PADW;
            float v = 0.f;
            int gy = iy0 + sy, gx = ix0 + sx;
            if (sx < PR && gy >= 0 && gy < H && gx >= 0 && gx < W)
                v = ip[(size_t)gy * W + gx];
            patch[t] = v;
        }
        __syncthreads();
        if (active) {
            float r[RW][RW];
            #pragma unroll
            for (int rr = 0; rr < RW; rr++) {
                int rowbase = (2 * ty * STRIDE + rr) * PADW + 2 * tx * STRIDE;
                if (STRIDE == 1) {
                    float2 a = *(const float2*)&patch[rowbase];
                    float2 c = *(const float2*)&patch[rowbase + 2];
                    r[rr][0] = a.x; r[rr][1] = a.y; r[rr][2] = c.x; r[rr][3] = c.y;
                } else {
                    float4 a = *(const float4*)&patch[rowbase];
                    r[rr][0] = a.x; r[rr][1] = a.y; r[rr][2] = a.z; r[rr][3] = a.w;
                    r[rr][4] = patch[rowbase + 4];
                }
            }
            const float* wb = wgt + ((size_t)co0 * Cin + ci) * 9;
            #pragma unroll
            for (int i = 0; i < COPB; i++) {
                const float* wp = wb + (size_t)i * Cin * 9;
                #pragma unroll
                for (int ki = 0; ki < 3; ki++)
                    #pragma unroll
                    for (int kj = 0; kj < 3; kj++) {
                        float w = wp[ki * 3 + kj];
                        acc[i][0] = fmaf(r[ki][kj],                  w, acc[i][0]);
                        acc[i][1] = fmaf(r[ki][kj + STRIDE],         w, acc[i][1]);
                        acc[i][2] = fmaf(r[ki + STRIDE][kj],         w, acc[i][2]);
                        acc[i][3] = fmaf(r[ki + STRIDE][kj + STRIDE],w, acc[i][3]);
                    }
            }
        }
        __syncthreads();
    }
    if (active) {
        #pragma unroll
        for (int rr = 0; rr < 2; rr++) {
            #pragma unroll
            for (int cc = 0; cc < 2; cc++) {
                int oy = py + rr, ox = px + cc;
                if (oy < Ho && ox < Wo) {
                    #pragma unroll
                    for (int i = 0; i < COPB; i++) {
                        float v = acc[i][rr * 2 + cc];
                        if (do_relu) v = fmaxf(v, 0.f);
                        out[(((size_t)b * Cout + co0 + i) * Ho + oy) * Wo + ox] = v;
                    }
                }
            }
        }
    }
}

// ---------------------------------------------------------------------------
// FUSED BN-apply + offset-conv + deformable bilinear resample.
// Input x is the RAW conv+relu output; BN affine (from stats/g/be) is applied
// during patch staging and to gathered samples (lerp commutes with affine).
// Reference reshape semantics (verified exact in round 3): conv pixel pair
// (p even, p+1) of conv channel 2c+half gives (oi, oj) for output pixel
// q = half*HW/2 + p/2; bilinear grid anchored at (q/W, q%W).
// Each thread owns a 2x2 conv-pixel quad with px even => both pixels of each
// pair are in-register: no LDS staging of conv results needed.
// Block: 28x28 conv-pixel tile, CP channel pairs (2*CP conv channels).
// Grid: (W/28, H/28, B*C/CP).
// ---------------------------------------------------------------------------
template<int CP>
__global__ __launch_bounds__(256) void offdeform_kernel(
    const float* __restrict__ x, const float* __restrict__ woff,
    const float* __restrict__ stats, const float* __restrict__ g,
    const float* __restrict__ be, float inv_cnt,
    float* __restrict__ out, int B, int C, int H, int W)
{
    constexpr int TILE = 28, PR = 30, PADW = 32;
    __shared__ float patch[PR * PADW];

    int groups = C / CP;
    int z  = blockIdx.z;
    int gi = z % groups, b = z / groups;
    int c0 = gi * CP;
    int tid = threadIdx.x;
    int pi0 = blockIdx.y * TILE, pj0 = blockIdx.x * TILE;
    int iy0 = pi0 - 1, ix0 = pj0 - 1;

    bool active = tid < 196;
    int ty = tid / 14, tx = tid % 14;
    int py = pi0 + 2 * ty, px = pj0 + 2 * tx;   // conv-pixel quad origin (px even)

    const int HW = H * W;
    const float* xb = x + (size_t)b * C * HW;

    float acc[2 * CP][4];
    #pragma unroll
    for (int i = 0; i < 2 * CP; i++)
        #pragma unroll
        for (int j = 0; j < 4; j++) acc[i][j] = 0.f;

    for (int ci = 0; ci < C; ci++) {
        float m  = stats[ci] * inv_cnt;
        float vv = stats[C + ci] * inv_cnt - m * m;
        float sc = g[ci] / sqrtf(vv + BN_EPS);
        float sh = be[ci] - m * sc;
        const float* ip = xb + (size_t)ci * HW;
        for (int t = tid; t < PR * PADW; t += 256) {
            int sy = t >> 5, sx = t & 31;
            float v = 0.f;
            int gy = iy0 + sy, gx = ix0 + sx;
            if (sx < PR && gy >= 0 && gy < H && gx >= 0 && gx < W)
                v = ip[(size_t)gy * W + gx] * sc + sh;
            patch[t] = v;
        }
        __syncthreads();
        if (active) {
            float r[4][4];
            #pragma unroll
            for (int rr = 0; rr < 4; rr++) {
                int rowbase = (2 * ty + rr) * PADW + 2 * tx;
                float2 a = *(const float2*)&patch[rowbase];
                float2 c = *(const float2*)&patch[rowbase + 2];
                r[rr][0] = a.x; r[rr][1] = a.y; r[rr][2] = c.x; r[rr][3] = c.y;
            }
            const float* wb = woff + ((size_t)(2 * c0) * C + ci) * 9;
            #pragma unroll
            for (int ch = 0; ch < 2 * CP; ch++) {
                const float* wp = wb + (size_t)ch * C * 9;
                #pragma unroll
                for (int ki = 0; ki < 3; ki++)
                    #pragma unroll
                    for (int kj = 0; kj < 3; kj++) {
                        float w = wp[ki * 3 + kj];
                        acc[ch][0] = fmaf(r[ki][kj],         w, acc[ch][0]);
                        acc[ch][1] = fmaf(r[ki][kj + 1],     w, acc[ch][1]);
                        acc[ch][2] = fmaf(r[ki + 1][kj],     w, acc[ch][2]);
                        acc[ch][3] = fmaf(r[ki + 1][kj + 1], w, acc[ch][3]);
                    }
            }
        }
        __syncthreads();
    }

    if (!active) return;

    // Per-channel BN affine for the gathered samples.
    float scc[CP], shc[CP];
    #pragma unroll
    for (int pp = 0; pp < CP; pp++) {
        int c = c0 + pp;
        float m  = stats[c] * inv_cnt;
        float vv = stats[C + c] * inv_cnt - m * m;
        scc[pp] = g[c] / sqrtf(vv + BN_EPS);
        shc[pp] = be[c] - m * scc[pp];
    }

    #pragma unroll
    for (int rr = 0; rr < 2; rr++) {
        int prow = py + rr;
        if (prow >= H) continue;
        int p0 = prow * W + px;               // even
        int qb = p0 >> 1;
        #pragma unroll
        for (int half = 0; half < 2; half++) {
            int q  = half * (HW >> 1) + qb;
            int qi = q / W, qj = q % W;
            #pragma unroll
            for (int pp = 0; pp < CP; pp++) {
                float oi = acc[2 * pp + half][rr * 2 + 0];
                float oj = acc[2 * pp + half][rr * 2 + 1];
                float ci_ = fminf(fmaxf(oi + (float)qi, 0.f), (float)(H - 1));
                float cj_ = fminf(fmaxf(oj + (float)qj, 0.f), (float)(W - 1));
                float i0f = floorf(ci_), j0f = floorf(cj_);
                int i0 = (int)i0f, i1 = (int)ceilf(ci_);
                int j0 = (int)j0f, j1 = (int)ceilf(cj_);
                const float* xp = xb + (size_t)(c0 + pp) * HW;
                float v00 = xp[i0 * W + j0];
                float v10 = xp[i1 * W + j0];
                float v01 = xp[i0 * W + j1];
                float v11 = xp[i1 * W + j1];
                float di = ci_ - i0f, dj = cj_ - j0f;
                float top = v00 + di * (v10 - v00);
                float bot = v01 + di * (v11 - v01);
                float res = top + dj * (bot - top);
                out[((size_t)b * C + c0 + pp) * HW + q] = res * scc[pp] + shc[pp];
            }
        }
    }
}

// ---------------------------------------------------------------------------
// BN batch statistics: per-channel sum and sum-of-squares (over N,H,W).
// ---------------------------------------------------------------------------
__global__ __launch_bounds__(256) void bn_stats_kernel(
    const float* __restrict__ x, float* __restrict__ stats,
    int B, int C, int HW)
{
    int c = blockIdx.x;
    long long cnt = (long long)B * HW;
    long long step = (long long)gridDim.y * blockDim.x;
    float s = 0.f, s2 = 0.f;
    for (long long t = (long long)blockIdx.y * blockDim.x + threadIdx.x; t < cnt; t += step) {
        int b  = (int)(t / HW);
        int sp = (int)(t % HW);
        float v = x[((size_t)b * C + c) * (size_t)HW + sp];
        s += v; s2 += v * v;
    }
    for (int off = 32; off; off >>= 1) {
        s  += __shfl_down(s, off);
        s2 += __shfl_down(s2, off);
    }
    __shared__ float ls[4], ls2[4];
    int wave = threadIdx.x >> 6, lane = threadIdx.x & 63;
    if (lane == 0) { ls[wave] = s; ls2[wave] = s2; }
    __syncthreads();
    if (threadIdx.x == 0) {
        float ts = 0.f, ts2 = 0.f;
        for (int i = 0; i < 4; i++) { ts += ls[i]; ts2 += ls2[i]; }
        atomicAdd(&stats[c], ts);
        atomicAdd(&stats[C + c], ts2);
    }
}

// ---------------------------------------------------------------------------
__global__ void zero_kernel(float* __restrict__ p, int n)
{
    int i = blockIdx.x * blockDim.x + threadIdx.x;
    if (i < n) p[i] = 0.f;
}

// ---------------------------------------------------------------------------
// Global average pool with fused BN affine: out = mean_raw*sc + sh.
// One block per (b,c).
// ---------------------------------------------------------------------------
__global__ __launch_bounds__(256) void pool_kernel(
    const float* __restrict__ x, const float* __restrict__ stats,
    const float* __restrict__ g, const float* __restrict__ be,
    float inv_cnt, float* __restrict__ out, int C, int HW)
{
    int bc = blockIdx.x;
    int c  = bc % C;
    const float* xp = x + (size_t)bc * HW;
    float s = 0.f;
    for (int i = threadIdx.x; i < HW; i += blockDim.x) s += xp[i];
    for (int off = 32; off; off >>= 1) s += __shfl_down(s, off);
    __shared__ float ls[4];
    int wave = threadIdx.x >> 6, lane = threadIdx.x & 63;
    if (lane == 0) ls[wave] = s;
    __syncthreads();
    if (threadIdx.x == 0) {
        float t = 0.f;
        for (int i = 0; i < 4; i++) t += ls[i];
        float mean = t / (float)HW;
        float m  = stats[c] * inv_cnt;
        float vv = stats[C + c] * inv_cnt - m * m;
        float sc = g[c] / sqrtf(vv + BN_EPS);
        float sh = be[c] - m * sc;
        out[bc] = mean * sc + sh;
    }
}

// ---------------------------------------------------------------------------
// FC (128 -> 10) + softmax per batch row. Block = 128 threads, grid = B.
// ---------------------------------------------------------------------------
__global__ __launch_bounds__(128) void fc_softmax_kernel(
    const float* __restrict__ pool, const float* __restrict__ wfc,
    const float* __restrict__ bfc, float* __restrict__ out)
{
    int b = blockIdx.x;
    __shared__ float row[128];
    __shared__ float logits[10];
    int tid = threadIdx.x;
    row[tid] = pool[b * 128 + tid];
    __syncthreads();
    if (tid < 10) {
        float s = bfc[tid];
        for (int k = 0; k < 128; k++) s = fmaf(row[k], wfc[tid * 128 + k], s);
        logits[tid] = s;
    }
    __syncthreads();
    if (tid < 10) {
        float mx = logits[0];
        for (int i = 1; i < 10; i++) mx = fmaxf(mx, logits[i]);
        float sum = 0.f;
        for (int i = 0; i < 10; i++) sum += expf(logits[i] - mx);
        out[b * 10 + tid] = expf(logits[tid] - mx) / sum;
    }
}

// ---------------------------------------------------------------------------
extern "C" void kernel_launch(void* const* d_in, const int* in_sizes, int n_in,
                              void* d_out, int out_size, void* d_ws, size_t ws_size,
                              hipStream_t stream)
{
    const float* x      = (const float*)d_in[0];
    const float* w11    = (const float*)d_in[1];
    const float* b11    = (const float*)d_in[2];
    const float* g11    = (const float*)d_in[3];
    const float* be11   = (const float*)d_in[4];
    const float* woff12 = (const float*)d_in[5];
    const float* w12    = (const float*)d_in[6];
    const float* b12    = (const float*)d_in[7];
    const float* g12    = (const float*)d_in[8];
    const float* be12   = (const float*)d_in[9];
    const float* woff21 = (const float*)d_in[10];
    const float* w21    = (const float*)d_in[11];
    const float* b21    = (const float*)d_in[12];
    const float* g21    = (const float*)d_in[13];
    const float* be21   = (const float*)d_in[14];
    const float* woff22 = (const float*)d_in[15];
    const float* w22    = (const float*)d_in[16];
    const float* b22    = (const float*)d_in[17];
    const float* g22    = (const float*)d_in[18];
    const float* be22   = (const float*)d_in[19];
    const float* wfc    = (const float*)d_in[20];
    const float* bfc    = (const float*)d_in[21];
    float* out = (float*)d_out;

    // Arena (floats): two ping-pong activation buffers of SZ_B = 25,690,112
    // floats (= 64*32*112*112 = 64*128*56*56) + stats(512) + pool(8192).
    // Total = 205,555,712 bytes.
    float* ws    = (float*)d_ws;
    const size_t SZ_B = 25690112;
    float* Bbuf  = ws;
    float* Cbuf  = Bbuf + SZ_B;
    float* stats = Cbuf + SZ_B;
    float* poolb = stats + 512;

    const int B = 64;

    // ---- Layer 1.1: conv(1->32, s1) + relu -> Bbuf (raw); stats ----
    conv3x3_kernel<1><<<dim3(4, 4, B * (32 / 8)), 256, 0, stream>>>(
        x, w11, b11, Bbuf, B, 1, 112, 112, 32, 112, 112, 1);
    zero_kernel<<<2, 256, 0, stream>>>(stats, 512);
    bn_stats_kernel<<<dim3(32, 64), 256, 0, stream>>>(Bbuf, stats, B, 32, 12544);

    // ---- deform12 (BN(1.1) fused + offconv 32->64 + resample): Bbuf -> Cbuf
    offdeform_kernel<4><<<dim3(4, 4, B * (32 / 4)), 256, 0, stream>>>(
        Bbuf, woff12, stats, g11, be11, 1.f / (64.f * 12544.f),
        Cbuf, B, 32, 112, 112);

    // ---- Layer 1.2: conv(32->64, s2) + relu -> Bbuf (raw); stats ----
    conv3x3_kernel<2><<<dim3(2, 2, B * (64 / 8)), 256, 0, stream>>>(
        Cbuf, w12, b12, Bbuf, B, 32, 112, 112, 64, 56, 56, 1);
    zero_kernel<<<2, 256, 0, stream>>>(stats, 512);
    bn_stats_kernel<<<dim3(64, 64), 256, 0, stream>>>(Bbuf, stats, B, 64, 3136);

    // ---- deform21 (BN(1.2) fused): Bbuf -> Cbuf ----
    offdeform_kernel<4><<<dim3(2, 2, B * (64 / 4)), 256, 0, stream>>>(
        Bbuf, woff21, stats, g12, be12, 1.f / (64.f * 3136.f),
        Cbuf, B, 64, 56, 56);

    // ---- Layer 2.1: conv(64->128, s1) + relu -> Bbuf (raw); stats ----
    conv3x3_kernel<1><<<dim3(2, 2, B * (128 / 8)), 256, 0, stream>>>(
        Cbuf, w21, b21, Bbuf, B, 64, 56, 56, 128, 56, 56, 1);
    zero_kernel<<<2, 256, 0, stream>>>(stats, 512);
    bn_stats_kernel<<<dim3(128, 64), 256, 0, stream>>>(Bbuf, stats, B, 128, 3136);

    // ---- deform22 (BN(2.1) fused): Bbuf -> Cbuf ----
    offdeform_kernel<4><<<dim3(2, 2, B * (128 / 4)), 256, 0, stream>>>(
        Bbuf, woff22, stats, g21, be21, 1.f / (64.f * 3136.f),
        Cbuf, B, 128, 56, 56);

    // ---- Layer 2.2: conv(128->128, s2) + relu -> Bbuf (raw); stats ----
    conv3x3_kernel<2><<<dim3(1, 1, B * (128 / 8)), 256, 0, stream>>>(
        Cbuf, w22, b22, Bbuf, B, 128, 56, 56, 128, 28, 28, 1);
    zero_kernel<<<2, 256, 0, stream>>>(stats, 512);
    bn_stats_kernel<<<dim3(128, 64), 256, 0, stream>>>(Bbuf, stats, B, 128, 784);

    // ---- Pool (BN(2.2) fused) + FC + softmax ----
    pool_kernel<<<B * 128, 256, 0, stream>>>(
        Bbuf, stats, g22, be22, 1.f / (64.f * 784.f), poolb, 128, 784);
    fc_softmax_kernel<<<B, 128, 0, stream>>>(poolb, wfc, bfc, out);
}

// Round 6
// 4565.578 us; speedup vs baseline: 3.3866x; 1.2172x over previous
//
#include <hip/hip_runtime.h>
#include <math.h>

#define BN_EPS 1e-5f

typedef unsigned short ushort_t;
typedef __attribute__((ext_vector_type(8))) short short8;     // 8 bf16 (4 VGPR)
typedef __attribute__((ext_vector_type(16))) float floatx16;  // MFMA 32x32 acc

// Split fp32 into bf16 hi (bit-truncate, exact) + bf16 lo (truncated remainder).
// a ~= hi + lo with relative error ~2^-16.
__device__ __forceinline__ void split_bf16(float v, ushort_t& h, ushort_t& l) {
    unsigned u = __float_as_uint(v);
    float fhi = __uint_as_float(u & 0xFFFF0000u);
    h = (ushort_t)(u >> 16);
    l = (ushort_t)(__float_as_uint(v - fhi) >> 16);
}

// ---------------------------------------------------------------------------
// Weight prep: OIHW fp32 -> [tap][O][I] bf16 hi/lo arrays (B-fragment-ready:
// lane reads 8 consecutive ci at fixed co via global dwordx4).
// ---------------------------------------------------------------------------
__global__ __launch_bounds__(256) void prep_w_kernel(
    const float* __restrict__ w, ushort_t* __restrict__ hi,
    ushort_t* __restrict__ lo, int O, int I)
{
    int idx = blockIdx.x * 256 + threadIdx.x;
    int n = 9 * O * I;
    if (idx >= n) return;
    int i = idx % I;
    int rest = idx / I;
    int o = rest % O;
    int t = rest / O;
    float v = w[((size_t)o * I + i) * 9 + t];
    split_bf16(v, hi[idx], lo[idx]);
}

// ---------------------------------------------------------------------------
// BN affine finalize: stats -> per-channel (sc, sh) pairs in aff[2c],[2c+1].
// ---------------------------------------------------------------------------
__global__ void bn_finalize_kernel(
    const float* __restrict__ stats, const float* __restrict__ g,
    const float* __restrict__ be, float inv_cnt, float* __restrict__ aff, int C)
{
    int c = threadIdx.x;
    if (c < C) {
        float m  = stats[c] * inv_cnt;
        float vv = stats[C + c] * inv_cnt - m * m;
        float sc = g[c] / sqrtf(vv + BN_EPS);
        aff[2 * c]     = sc;
        aff[2 * c + 1] = be[c] - m * sc;
    }
}

// ---------------------------------------------------------------------------
// MFMA 3x3 conv (stride 1), split-bf16 fp32 emulation (Ah*Bh + Ah*Bl + Al*Bh).
// Block = 128 threads (2 waves). M = 64 consecutive linear pixels (wave w owns
// pixels p0+32w..+31; HW%64==0 so no image straddle; <=2 pixel rows -> 4-row
// LDS patch). N = 32*NT conv channels (wave computes 1 M-tile x NT N-tiles).
// A: LDS patch [row][col][ci16] bf16 hi/lo, ds_read_b128 frags
//    (A[m=lane&31][k=(lane>>5)*8+j], verified gfx950 mapping family).
// B: pre-split weights [tap][CO][CIN], global dwordx4 per frag
//    (B[k=(lane>>5)*8+j][n=lane&31]).
// acc: f32, C/D row=(reg&3)+8*(reg>>2)+4*(lane>>5), col=lane&31 [m74/m101].
// DEFORM epilogue: conv-pixel pair (p even, p+1) of conv channel 2c+half give
// (oi,oj) for output q = half*HW/2 + p/2 (round-3-verified reshape
// semantics); the pair sits in adjacent acc regs of one lane. BNIN applies
// aff to staged input and to gathered samples.
// BREL epilogue: plain conv store with bias+relu.
// ---------------------------------------------------------------------------
template<int W, int H, int CIN, int CO, int NT, bool DEFORM, bool BNIN, bool BREL>
__global__ __launch_bounds__(128) void mfma_conv_kernel(
    const float* __restrict__ x, const ushort_t* __restrict__ wh,
    const ushort_t* __restrict__ wl, const float* __restrict__ aff,
    const float* __restrict__ bias, float* __restrict__ out)
{
    constexpr int PADC = W + 2;
    constexpr int PSZ  = 4 * PADC * 16;        // 4 rows x (W+2) cols x 16 ci
    __shared__ __align__(16) ushort_t patch_h[PSZ];
    __shared__ __align__(16) ushort_t patch_l[PSZ];

    const int tid  = threadIdx.x;
    const int wv   = tid >> 6;                 // wave -> M-tile
    const int lane = tid & 63;
    const int l31  = lane & 31;
    const int kg   = lane >> 5;                // k-group (0/1)
    const int p0   = blockIdx.x * 64;
    const int b    = blockIdx.y;
    const int n0   = blockIdx.z * (NT * 32);
    const int HWc  = H * W;

    const int mp = p0 + wv * 32 + l31;         // this lane's pixel (A row m)
    const int py = mp / W, px = mp % W;
    const int r0 = p0 / W;                     // first pixel row of block
    const int abase = ((py - r0) * PADC + px) * 16 + kg * 8;

    const float* xb = x + (size_t)b * CIN * HWc;

    floatx16 acc[NT];
    #pragma unroll
    for (int nt = 0; nt < NT; nt++)
        #pragma unroll
        for (int i = 0; i < 16; i++) acc[nt][i] = 0.f;

    const int nchunks = CIN / 16;
    for (int ch = 0; ch < nchunks; ch++) {
        const int ci0 = ch * 16;
        // ---- stage patch (coalesced: col fastest) ----
        for (int t = tid; t < PSZ; t += 128) {
            int col = t % PADC;
            int row = (t / PADC) % 4;
            int ci  = t / (4 * PADC);
            int gy = r0 - 1 + row, gx = col - 1;
            float v = 0.f;
            if (gy >= 0 && gy < H && gx >= 0 && gx < W) {
                v = xb[(size_t)(ci0 + ci) * HWc + gy * W + gx];
                if (BNIN) v = fmaf(v, aff[2 * (ci0 + ci)], aff[2 * (ci0 + ci) + 1]);
            }
            int slot = (row * PADC + col) * 16 + ci;
            split_bf16(v, patch_h[slot], patch_l[slot]);
        }
        __syncthreads();
        // ---- 9 taps x NT tiles x 3 split-MFMAs ----
        #pragma unroll
        for (int ki = 0; ki < 3; ki++) {
            #pragma unroll
            for (int kj = 0; kj < 3; kj++) {
                const int tap  = ki * 3 + kj;
                const int aoff = abase + (ki * PADC + kj) * 16;
                short8 a_h = *(const short8*)&patch_h[aoff];
                short8 a_l = *(const short8*)&patch_l[aoff];
                #pragma unroll
                for (int nt = 0; nt < NT; nt++) {
                    int co = n0 + nt * 32 + l31;
                    size_t widx = ((size_t)tap * CO + co) * CIN + ci0 + kg * 8;
                    short8 b_h = *(const short8*)(wh + widx);
                    short8 b_l = *(const short8*)(wl + widx);
                    acc[nt] = __builtin_amdgcn_mfma_f32_32x32x16_bf16(a_h, b_h, acc[nt], 0, 0, 0);
                    acc[nt] = __builtin_amdgcn_mfma_f32_32x32x16_bf16(a_h, b_l, acc[nt], 0, 0, 0);
                    acc[nt] = __builtin_amdgcn_mfma_f32_32x32x16_bf16(a_l, b_h, acc[nt], 0, 0, 0);
                }
            }
        }
        __syncthreads();
    }

    if (DEFORM) {
        // acc[nt][2t], [2t+1] = conv channel co at even pixel p and p+1.
        #pragma unroll
        for (int nt = 0; nt < NT; nt++) {
            int gch  = n0 + nt * 32 + l31;      // conv channel
            int c    = gch >> 1, half = gch & 1;
            float sc = aff[2 * c], sh = aff[2 * c + 1];
            const float* xp = xb + (size_t)c * HWc;
            #pragma unroll
            for (int t = 0; t < 8; t++) {
                int reg0 = 2 * t;
                int row  = (reg0 & 3) + 8 * (reg0 >> 2) + 4 * kg;
                int p    = p0 + wv * 32 + row;  // even
                float oi = acc[nt][reg0];
                float oj = acc[nt][reg0 + 1];
                int q  = half * (HWc >> 1) + (p >> 1);
                int qi = q / W, qj = q % W;
                float ci_ = fminf(fmaxf(oi + (float)qi, 0.f), (float)(H - 1));
                float cj_ = fminf(fmaxf(oj + (float)qj, 0.f), (float)(W - 1));
                float i0f = floorf(ci_), j0f = floorf(cj_);
                int i0 = (int)i0f, i1 = (int)ceilf(ci_);
                int j0 = (int)j0f, j1 = (int)ceilf(cj_);
                float v00 = xp[i0 * W + j0];
                float v10 = xp[i1 * W + j0];
                float v01 = xp[i0 * W + j1];
                float v11 = xp[i1 * W + j1];
                float di = ci_ - i0f, dj = cj_ - j0f;
                float top = v00 + di * (v10 - v00);
                float bot = v01 + di * (v11 - v01);
                float res = top + dj * (bot - top);
                out[((size_t)b * CIN + c) * HWc + q] = res * sc + sh;
            }
        }
    }
    if (BREL) {
        #pragma unroll
        for (int nt = 0; nt < NT; nt++) {
            int co = n0 + nt * 32 + l31;
            float bv = bias[co];
            #pragma unroll
            for (int reg = 0; reg < 16; reg++) {
                int row = (reg & 3) + 8 * (reg >> 2) + 4 * kg;
                int p   = p0 + wv * 32 + row;
                out[((size_t)b * CO + co) * HWc + p] = fmaxf(acc[nt][reg] + bv, 0.f);
            }
        }
    }
}

// ---------------------------------------------------------------------------
// Vector direct 3x3 conv (kept for conv11 and the stride-2 convs).
// ---------------------------------------------------------------------------
template<int STRIDE>
__global__ __launch_bounds__(256) void conv3x3_kernel(
    const float* __restrict__ in, const float* __restrict__ wgt,
    const float* __restrict__ bias, float* __restrict__ out,
    int B, int Cin, int H, int W, int Cout, int Ho, int Wo, int do_relu)
{
    constexpr int TILE = 28;
    constexpr int PR   = (TILE - 1) * STRIDE + 3;
    constexpr int PADW = (STRIDE == 1) ? 32 : 60;
    constexpr int COPB = 8;
    constexpr int RW   = STRIDE + 3;
    __shared__ float patch[PR * PADW];

    int cpg  = Cout / COPB;
    int bz   = blockIdx.z;
    int cog  = bz % cpg;
    int b    = bz / cpg;
    int co0  = cog * COPB;
    int tid  = threadIdx.x;
    int oy0  = blockIdx.y * TILE, ox0 = blockIdx.x * TILE;
    int iy0  = oy0 * STRIDE - 1,  ix0 = ox0 * STRIDE - 1;

    bool active = tid < 196;
    int ty = tid / 14, tx = tid % 14;
    int py = oy0 + 2 * ty, px = ox0 + 2 * tx;

    float acc[COPB][4];
    #pragma unroll
    for (int i = 0; i < COPB; i++) {
        float bv = bias ? bias[co0 + i] : 0.f;
        #pragma unroll
        for (int j = 0; j < 4; j++) acc[i][j] = bv;
    }

    const size_t HW = (size_t)H * W;
    for (int ci = 0; ci < Cin; ci++) {
        const float* ip = in + ((size_t)b * Cin + ci) * HW;
        for (int t = tid; t < PR * PADW; t += 256) {
            int sy = t / PADW, sx = t % PADW;
            float v = 0.f;
            int gy = iy0 + sy, gx = ix0 + sx;
            if (sx < PR && gy >= 0 && gy < H && gx >= 0 && gx < W)
                v = ip[(size_t)gy * W + gx];
            patch[t] = v;
        }
        __syncthreads();
        if (active) {
            float r[RW][RW];
            #pragma unroll
            for (int rr = 0; rr < RW; rr++) {
                int rowbase = (2 * ty * STRIDE + rr) * PADW + 2 * tx * STRIDE;
                if (STRIDE == 1) {
                    float2 a = *(const float2*)&patch[rowbase];
                    float2 c = *(const float2*)&patch[rowbase + 2];
                    r[rr][0] = a.x; r[rr][1] = a.y; r[rr][2] = c.x; r[rr][3] = c.y;
                } else {
                    float4 a = *(const float4*)&patch[rowbase];
                    r[rr][0] = a.x; r[rr][1] = a.y; r[rr][2] = a.z; r[rr][3] = a.w;
                    r[rr][4] = patch[rowbase + 4];
                }
            }
            const float* wb = wgt + ((size_t)co0 * Cin + ci) * 9;
            #pragma unroll
            for (int i = 0; i < COPB; i++) {
                const float* wp = wb + (size_t)i * Cin * 9;
                #pragma unroll
                for (int ki = 0; ki < 3; ki++)
                    #pragma unroll
                    for (int kj = 0; kj < 3; kj++) {
                        float w = wp[ki * 3 + kj];
                        acc[i][0] = fmaf(r[ki][kj],                   w, acc[i][0]);
                        acc[i][1] = fmaf(r[ki][kj + STRIDE],          w, acc[i][1]);
                        acc[i][2] = fmaf(r[ki + STRIDE][kj],          w, acc[i][2]);
                        acc[i][3] = fmaf(r[ki + STRIDE][kj + STRIDE], w, acc[i][3]);
                    }
            }
        }
        __syncthreads();
    }
    if (active) {
        #pragma unroll
        for (int rr = 0; rr < 2; rr++) {
            #pragma unroll
            for (int cc = 0; cc < 2; cc++) {
                int oy = py + rr, ox = px + cc;
                if (oy < Ho && ox < Wo) {
                    #pragma unroll
                    for (int i = 0; i < COPB; i++) {
                        float v = acc[i][rr * 2 + cc];
                        if (do_relu) v = fmaxf(v, 0.f);
                        out[(((size_t)b * Cout + co0 + i) * Ho + oy) * Wo + ox] = v;
                    }
                }
            }
        }
    }
}

// ---------------------------------------------------------------------------
__global__ __launch_bounds__(256) void bn_stats_kernel(
    const float* __restrict__ x, float* __restrict__ stats,
    int B, int C, int HW)
{
    int c = blockIdx.x;
    long long cnt = (long long)B * HW;
    long long step = (long long)gridDim.y * blockDim.x;
    float s = 0.f, s2 = 0.f;
    for (long long t = (long long)blockIdx.y * blockDim.x + threadIdx.x; t < cnt; t += step) {
        int b  = (int)(t / HW);
        int sp = (int)(t % HW);
        float v = x[((size_t)b * C + c) * (size_t)HW + sp];
        s += v; s2 += v * v;
    }
    for (int off = 32; off; off >>= 1) {
        s  += __shfl_down(s, off);
        s2 += __shfl_down(s2, off);
    }
    __shared__ float ls[4], ls2[4];
    int wave = threadIdx.x >> 6, lane = threadIdx.x & 63;
    if (lane == 0) { ls[wave] = s; ls2[wave] = s2; }
    __syncthreads();
    if (threadIdx.x == 0) {
        float ts = 0.f, ts2 = 0.f;
        for (int i = 0; i < 4; i++) { ts += ls[i]; ts2 += ls2[i]; }
        atomicAdd(&stats[c], ts);
        atomicAdd(&stats[C + c], ts2);
    }
}

// ---------------------------------------------------------------------------
__global__ void zero_kernel(float* __restrict__ p, int n)
{
    int i = blockIdx.x * blockDim.x + threadIdx.x;
    if (i < n) p[i] = 0.f;
}

// ---------------------------------------------------------------------------
__global__ __launch_bounds__(256) void pool_kernel(
    const float* __restrict__ x, const float* __restrict__ stats,
    const float* __restrict__ g, const float* __restrict__ be,
    float inv_cnt, float* __restrict__ out, int C, int HW)
{
    int bc = blockIdx.x;
    int c  = bc % C;
    const float* xp = x + (size_t)bc * HW;
    float s = 0.f;
    for (int i = threadIdx.x; i < HW; i += blockDim.x) s += xp[i];
    for (int off = 32; off; off >>= 1) s += __shfl_down(s, off);
    __shared__ float ls[4];
    int wave = threadIdx.x >> 6, lane = threadIdx.x & 63;
    if (lane == 0) ls[wave] = s;
    __syncthreads();
    if (threadIdx.x == 0) {
        float t = 0.f;
        for (int i = 0; i < 4; i++) t += ls[i];
        float mean = t / (float)HW;
        float m  = stats[c] * inv_cnt;
        float vv = stats[C + c] * inv_cnt - m * m;
        float sc = g[c] / sqrtf(vv + BN_EPS);
        float sh = be[c] - m * sc;
        out[bc] = mean * sc + sh;
    }
}

// ---------------------------------------------------------------------------
__global__ __launch_bounds__(128) void fc_softmax_kernel(
    const float* __restrict__ pool, const float* __restrict__ wfc,
    const float* __restrict__ bfc, float* __restrict__ out)
{
    int b = blockIdx.x;
    __shared__ float row[128];
    __shared__ float logits[10];
    int tid = threadIdx.x;
    row[tid] = pool[b * 128 + tid];
    __syncthreads();
    if (tid < 10) {
        float s = bfc[tid];
        for (int k = 0; k < 128; k++) s = fmaf(row[k], wfc[tid * 128 + k], s);
        logits[tid] = s;
    }
    __syncthreads();
    if (tid < 10) {
        float mx = logits[0];
        for (int i = 1; i < 10; i++) mx = fmaxf(mx, logits[i]);
        float sum = 0.f;
        for (int i = 0; i < 10; i++) sum += expf(logits[i] - mx);
        out[b * 10 + tid] = expf(logits[tid] - mx) / sum;
    }
}

// ---------------------------------------------------------------------------
extern "C" void kernel_launch(void* const* d_in, const int* in_sizes, int n_in,
                              void* d_out, int out_size, void* d_ws, size_t ws_size,
                              hipStream_t stream)
{
    const float* x      = (const float*)d_in[0];
    const float* w11    = (const float*)d_in[1];
    const float* b11    = (const float*)d_in[2];
    const float* g11    = (const float*)d_in[3];
    const float* be11   = (const float*)d_in[4];
    const float* woff12 = (const float*)d_in[5];
    const float* w12    = (const float*)d_in[6];
    const float* b12    = (const float*)d_in[7];
    const float* g12    = (const float*)d_in[8];
    const float* be12   = (const float*)d_in[9];
    const float* woff21 = (const float*)d_in[10];
    const float* w21    = (const float*)d_in[11];
    const float* b21    = (const float*)d_in[12];
    const float* g21    = (const float*)d_in[13];
    const float* be21   = (const float*)d_in[14];
    const float* woff22 = (const float*)d_in[15];
    const float* w22    = (const float*)d_in[16];
    const float* b22    = (const float*)d_in[17];
    const float* g22    = (const float*)d_in[18];
    const float* be22   = (const float*)d_in[19];
    const float* wfc    = (const float*)d_in[20];
    const float* bfc    = (const float*)d_in[21];
    float* out = (float*)d_out;

    // Arena: 2 ping-pong activation buffers (SZ_B floats each) + stats + aff
    // + pool + split-bf16 weight arrays. Total ~207.4 MB.
    float* ws    = (float*)d_ws;
    const size_t SZ_B = 25690112;   // 64*32*112*112 = 64*128*56*56 floats
    float* Bbuf  = ws;
    float* Cbuf  = Bbuf + SZ_B;
    float* stats = Cbuf + SZ_B;      // 512
    float* aff   = stats + 512;      // 512
    float* poolb = aff + 512;        // 8192
    ushort_t* warena = (ushort_t*)(poolb + 8192);
    const size_t W12 = 9 * 64 * 32;    // 18432
    const size_t W21 = 9 * 128 * 64;   // 73728
    const size_t W22 = 9 * 256 * 128;  // 294912
    ushort_t* wp12h = warena;          ushort_t* wp12l = wp12h + W12;
    ushort_t* wp21h = wp12l + W12;     ushort_t* wp21l = wp21h + W21;
    ushort_t* wc21h = wp21l + W21;     ushort_t* wc21l = wc21h + W21;
    ushort_t* wp22h = wc21l + W21;     ushort_t* wp22l = wp22h + W22;

    const int B = 64;

    // ---- weight prep (split bf16, [tap][O][I]) ----
    prep_w_kernel<<<(9 * 64 * 32 + 255) / 256, 256, 0, stream>>>(woff12, wp12h, wp12l, 64, 32);
    prep_w_kernel<<<(9 * 128 * 64 + 255) / 256, 256, 0, stream>>>(woff21, wp21h, wp21l, 128, 64);
    prep_w_kernel<<<(9 * 128 * 64 + 255) / 256, 256, 0, stream>>>(w21, wc21h, wc21l, 128, 64);
    prep_w_kernel<<<(9 * 256 * 128 + 255) / 256, 256, 0, stream>>>(woff22, wp22h, wp22l, 256, 128);

    // ---- Layer 1.1: conv(1->32, s1)+relu -> Bbuf raw; stats; finalize ----
    conv3x3_kernel<1><<<dim3(4, 4, B * (32 / 8)), 256, 0, stream>>>(
        x, w11, b11, Bbuf, B, 1, 112, 112, 32, 112, 112, 1);
    zero_kernel<<<2, 256, 0, stream>>>(stats, 512);
    bn_stats_kernel<<<dim3(32, 64), 256, 0, stream>>>(Bbuf, stats, B, 32, 12544);
    bn_finalize_kernel<<<1, 256, 0, stream>>>(stats, g11, be11, 1.f / (64.f * 12544.f), aff, 32);

    // ---- deform12 (MFMA): BN(1.1)-fused offconv 32->64 + resample ----
    mfma_conv_kernel<112, 112, 32, 64, 2, true, true, false>
        <<<dim3(196, B, 1), 128, 0, stream>>>(Bbuf, wp12h, wp12l, aff, nullptr, Cbuf);

    // ---- Layer 1.2: conv(32->64, s2)+relu -> Bbuf raw; stats; finalize ----
    conv3x3_kernel<2><<<dim3(2, 2, B * (64 / 8)), 256, 0, stream>>>(
        Cbuf, w12, b12, Bbuf, B, 32, 112, 112, 64, 56, 56, 1);
    zero_kernel<<<2, 256, 0, stream>>>(stats, 512);
    bn_stats_kernel<<<dim3(64, 64), 256, 0, stream>>>(Bbuf, stats, B, 64, 3136);
    bn_finalize_kernel<<<1, 256, 0, stream>>>(stats, g12, be12, 1.f / (64.f * 3136.f), aff, 64);

    // ---- deform21 (MFMA): BN(1.2)-fused offconv 64->128 + resample ----
    mfma_conv_kernel<56, 56, 64, 128, 4, true, true, false>
        <<<dim3(49, B, 1), 128, 0, stream>>>(Bbuf, wp21h, wp21l, aff, nullptr, Cbuf);

    // ---- Layer 2.1 (MFMA): conv(64->128, s1)+bias+relu -> Bbuf raw ----
    mfma_conv_kernel<56, 56, 64, 128, 4, false, false, true>
        <<<dim3(49, B, 1), 128, 0, stream>>>(Cbuf, wc21h, wc21l, nullptr, b21, Bbuf);
    zero_kernel<<<2, 256, 0, stream>>>(stats, 512);
    bn_stats_kernel<<<dim3(128, 64), 256, 0, stream>>>(Bbuf, stats, B, 128, 3136);
    bn_finalize_kernel<<<1, 256, 0, stream>>>(stats, g21, be21, 1.f / (64.f * 3136.f), aff, 128);

    // ---- deform22 (MFMA): BN(2.1)-fused offconv 128->256 + resample ----
    mfma_conv_kernel<56, 56, 128, 256, 4, true, true, false>
        <<<dim3(49, B, 2), 128, 0, stream>>>(Bbuf, wp22h, wp22l, aff, nullptr, Cbuf);

    // ---- Layer 2.2: conv(128->128, s2)+relu -> Bbuf raw; stats ----
    conv3x3_kernel<2><<<dim3(1, 1, B * (128 / 8)), 256, 0, stream>>>(
        Cbuf, w22, b22, Bbuf, B, 128, 56, 56, 128, 28, 28, 1);
    zero_kernel<<<2, 256, 0, stream>>>(stats, 512);
    bn_stats_kernel<<<dim3(128, 64), 256, 0, stream>>>(Bbuf, stats, B, 128, 784);

    // ---- Pool (BN(2.2) fused) + FC + softmax ----
    pool_kernel<<<B * 128, 256, 0, stream>>>(
        Bbuf, stats, g22, be22, 1.f / (64.f * 784.f), poolb, 128, 784);
    fc_softmax_kernel<<<B, 128, 0, stream>>>(poolb, wfc, bfc, out);
}

// Round 7
// 3870.779 us; speedup vs baseline: 3.9945x; 1.1795x over previous
//
#include <hip/hip_runtime.h>
#include <math.h>

#define BN_EPS 1e-5f

typedef unsigned short ushort_t;
typedef __attribute__((ext_vector_type(8))) short short8;     // 8 bf16 (4 VGPR)
typedef __attribute__((ext_vector_type(16))) float floatx16;  // MFMA 32x32 acc

// Split fp32 into bf16 hi (bit-truncate, exact) + bf16 lo (truncated remainder).
__device__ __forceinline__ void split_bf16(float v, ushort_t& h, ushort_t& l) {
    unsigned u = __float_as_uint(v);
    float fhi = __uint_as_float(u & 0xFFFF0000u);
    h = (ushort_t)(u >> 16);
    l = (ushort_t)(__float_as_uint(v - fhi) >> 16);
}

// ---------------------------------------------------------------------------
// Weight prep: OIHW fp32 -> [tap][O][I] bf16 hi/lo (B-fragment-ready).
// ---------------------------------------------------------------------------
__global__ __launch_bounds__(256) void prep_w_kernel(
    const float* __restrict__ w, ushort_t* __restrict__ hi,
    ushort_t* __restrict__ lo, int O, int I)
{
    int idx = blockIdx.x * 256 + threadIdx.x;
    int n = 9 * O * I;
    if (idx >= n) return;
    int i = idx % I;
    int rest = idx / I;
    int o = rest % O;
    int t = rest / O;
    float v = w[((size_t)o * I + i) * 9 + t];
    split_bf16(v, hi[idx], lo[idx]);
}

// ---------------------------------------------------------------------------
__global__ void bn_finalize_kernel(
    const float* __restrict__ stats, const float* __restrict__ g,
    const float* __restrict__ be, float inv_cnt, float* __restrict__ aff, int C)
{
    int c = threadIdx.x;
    if (c < C) {
        float m  = stats[c] * inv_cnt;
        float vv = stats[C + c] * inv_cnt - m * m;
        float sc = g[c] / sqrtf(vv + BN_EPS);
        aff[2 * c]     = sc;
        aff[2 * c + 1] = be[c] - m * sc;
    }
}

// ---------------------------------------------------------------------------
// MFMA 3x3 conv (stride 1), split-bf16 fp32 emulation (Ah*Bh + Ah*Bl + Al*Bh).
// Block = 128 threads (2 waves); wave = one 32-pixel M-tile, NT 32-ch N-tiles.
// Patch LDS layout [row][col][ci16] bf16 hi/lo; A-frags via ds_read_b128.
// B from pre-split weights [tap][CO][CIN], preloaded per tap (reg arrays).
// DBUF: double-buffered patch, prefetch chunk k+1 globals before MFMA(k),
// write after, one barrier per chunk. Staging: float4 loads over 2 ci planes
// (rows 16B-aligned since W%4==0), b32 ci-pair LDS writes (4-way conflicts).
// Halo cols (gx==-1, gx==W) are always OOB -> zeroed once up front.
// Epilogues (verified exact in rounds 3-6): DEFORM pair-in-lane remap + BN;
// BREL bias+relu store.
// ---------------------------------------------------------------------------
template<int W, int H, int CIN, int CO, int NT, bool DEFORM, bool BNIN, bool BREL, bool DBUF>
__global__ __launch_bounds__(128) void mfma_conv_kernel(
    const float* __restrict__ x, const ushort_t* __restrict__ wh,
    const ushort_t* __restrict__ wl, const float* __restrict__ aff,
    const float* __restrict__ bias, float* __restrict__ out)
{
    constexpr int PADC = W + 2;
    constexpr int PSZ  = 4 * PADC * 16;      // ushorts per buffer
    constexpr int NB   = DBUF ? 2 : 1;
    constexpr int NC4  = W / 4;
    constexpr int NIT  = 8 * 4 * NC4;        // cipair x row x c4 items per chunk
    constexpr int NCH  = CIN / 16;
    __shared__ __align__(16) ushort_t patch_h[NB][PSZ];
    __shared__ __align__(16) ushort_t patch_l[NB][PSZ];

    const int tid  = threadIdx.x;
    const int wv   = tid >> 6;
    const int lane = tid & 63;
    const int l31  = lane & 31;
    const int kg   = lane >> 5;
    const int p0   = blockIdx.x * 64;
    const int b    = blockIdx.y;
    const int n0   = blockIdx.z * (NT * 32);
    const int HWc  = H * W;

    const int mp = p0 + wv * 32 + l31;
    const int py = mp / W, px = mp % W;
    const int r0 = p0 / W;
    const int abase = ((py - r0) * PADC + px) * 16 + kg * 8;

    const float* xb = x + (size_t)b * CIN * HWc;

    // ---- zero halo cols (always OOB -> 0 for every chunk) ----
    for (int t = tid; t < NB * 128; t += 128) {
        int bb = t >> 7, r = (t >> 5) & 3, side = (t >> 4) & 1, ci = t & 15;
        int col = side ? (PADC - 1) : 0;
        int slot = (r * PADC + col) * 16 + ci;
        patch_h[bb][slot] = 0;
        patch_l[bb][slot] = 0;
    }

    floatx16 acc[NT];
    #pragma unroll
    for (int nt = 0; nt < NT; nt++)
        #pragma unroll
        for (int i = 0; i < 16; i++) acc[nt][i] = 0.f;

    // fused stage (load + BN + split + LDS write) for chunk ci0 into buf bb
    auto stage_fused = [&](int ci0, int bb) {
        for (int t = tid; t < NIT; t += 128) {
            int cp = t & 7, row = (t >> 3) & 3, c4 = t >> 5;
            int ci = 2 * cp;
            int gy = r0 - 1 + row, gx = 4 * c4;
            float4 v0 = {0.f, 0.f, 0.f, 0.f}, v1 = v0;
            if (gy >= 0 && gy < H) {
                v0 = *(const float4*)(xb + (size_t)(ci0 + ci) * HWc + gy * W + gx);
                v1 = *(const float4*)(xb + (size_t)(ci0 + ci + 1) * HWc + gy * W + gx);
                if (BNIN) {
                    float sc0 = aff[2 * (ci0 + ci)],     sh0 = aff[2 * (ci0 + ci) + 1];
                    float sc1 = aff[2 * (ci0 + ci) + 2], sh1 = aff[2 * (ci0 + ci) + 3];
                    v0.x = fmaf(v0.x, sc0, sh0); v0.y = fmaf(v0.y, sc0, sh0);
                    v0.z = fmaf(v0.z, sc0, sh0); v0.w = fmaf(v0.w, sc0, sh0);
                    v1.x = fmaf(v1.x, sc1, sh1); v1.y = fmaf(v1.y, sc1, sh1);
                    v1.z = fmaf(v1.z, sc1, sh1); v1.w = fmaf(v1.w, sc1, sh1);
                }
            }
            int base = (row * PADC + gx + 1) * 16 + ci;
            const float e0[4] = {v0.x, v0.y, v0.z, v0.w};
            const float e1[4] = {v1.x, v1.y, v1.z, v1.w};
            #pragma unroll
            for (int j = 0; j < 4; j++) {
                ushort_t h0, l0, h1, l1;
                split_bf16(e0[j], h0, l0);
                split_bf16(e1[j], h1, l1);
                *(ushort2*)&patch_h[bb][base + 16 * j] = make_ushort2(h0, h1);
                *(ushort2*)&patch_l[bb][base + 16 * j] = make_ushort2(l0, l1);
            }
        }
    };

    auto mfma_phase = [&](int bb, int ci0) {
        const ushort_t* ph = patch_h[bb];
        const ushort_t* pl = patch_l[bb];
        #pragma unroll
        for (int ki = 0; ki < 3; ki++) {
            #pragma unroll
            for (int kj = 0; kj < 3; kj++) {
                const int tap  = ki * 3 + kj;
                short8 bhv[NT], blv[NT];
                #pragma unroll
                for (int nt = 0; nt < NT; nt++) {
                    size_t widx = ((size_t)tap * CO + (n0 + nt * 32 + l31)) * CIN + ci0 + kg * 8;
                    bhv[nt] = *(const short8*)(wh + widx);
                    blv[nt] = *(const short8*)(wl + widx);
                }
                const int aoff = abase + (ki * PADC + kj) * 16;
                short8 a_h = *(const short8*)&ph[aoff];
                short8 a_l = *(const short8*)&pl[aoff];
                #pragma unroll
                for (int nt = 0; nt < NT; nt++) {
                    acc[nt] = __builtin_amdgcn_mfma_f32_32x32x16_bf16(a_h, bhv[nt], acc[nt], 0, 0, 0);
                    acc[nt] = __builtin_amdgcn_mfma_f32_32x32x16_bf16(a_h, blv[nt], acc[nt], 0, 0, 0);
                    acc[nt] = __builtin_amdgcn_mfma_f32_32x32x16_bf16(a_l, bhv[nt], acc[nt], 0, 0, 0);
                }
            }
        }
    };

    // ---- prologue: stage chunk 0 ----
    stage_fused(0, 0);
    __syncthreads();

    for (int ch = 0; ch < NCH; ch++) {
        const int bb = DBUF ? (ch & 1) : 0;
        if constexpr (DBUF) {
            const bool pfv = (ch + 1 < NCH);
            float4 pa[4], pb[4];
            if (pfv) {
                const int ci0n = (ch + 1) * 16;
                int k = 0;
                for (int t = tid; t < NIT; t += 128, k++) {
                    int cp = t & 7, row = (t >> 3) & 3, c4 = t >> 5;
                    int ci = 2 * cp;
                    int gy = r0 - 1 + row, gx = 4 * c4;
                    float4 v0 = {0.f, 0.f, 0.f, 0.f}, v1 = v0;
                    if (gy >= 0 && gy < H) {
                        v0 = *(const float4*)(xb + (size_t)(ci0n + ci) * HWc + gy * W + gx);
                        v1 = *(const float4*)(xb + (size_t)(ci0n + ci + 1) * HWc + gy * W + gx);
                        if (BNIN) {
                            float sc0 = aff[2 * (ci0n + ci)],     sh0 = aff[2 * (ci0n + ci) + 1];
                            float sc1 = aff[2 * (ci0n + ci) + 2], sh1 = aff[2 * (ci0n + ci) + 3];
                            v0.x = fmaf(v0.x, sc0, sh0); v0.y = fmaf(v0.y, sc0, sh0);
                            v0.z = fmaf(v0.z, sc0, sh0); v0.w = fmaf(v0.w, sc0, sh0);
                            v1.x = fmaf(v1.x, sc1, sh1); v1.y = fmaf(v1.y, sc1, sh1);
                            v1.z = fmaf(v1.z, sc1, sh1); v1.w = fmaf(v1.w, sc1, sh1);
                        }
                    }
                    pa[k] = v0; pb[k] = v1;
                }
            }
            mfma_phase(bb, ch * 16);
            if (pfv) {
                const int nb2 = (ch + 1) & 1;
                int k = 0;
                for (int t = tid; t < NIT; t += 128, k++) {
                    int cp = t & 7, row = (t >> 3) & 3, c4 = t >> 5;
                    int ci = 2 * cp;
                    int gx = 4 * c4;
                    int base = (row * PADC + gx + 1) * 16 + ci;
                    const float e0[4] = {pa[k].x, pa[k].y, pa[k].z, pa[k].w};
                    const float e1[4] = {pb[k].x, pb[k].y, pb[k].z, pb[k].w};
                    #pragma unroll
                    for (int j = 0; j < 4; j++) {
                        ushort_t h0, l0, h1, l1;
                        split_bf16(e0[j], h0, l0);
                        split_bf16(e1[j], h1, l1);
                        *(ushort2*)&patch_h[nb2][base + 16 * j] = make_ushort2(h0, h1);
                        *(ushort2*)&patch_l[nb2][base + 16 * j] = make_ushort2(l0, l1);
                    }
                }
            }
            __syncthreads();
        } else {
            mfma_phase(0, ch * 16);
            __syncthreads();
            if (ch + 1 < NCH) {
                stage_fused((ch + 1) * 16, 0);
                __syncthreads();
            }
        }
    }

    if (DEFORM) {
        #pragma unroll
        for (int nt = 0; nt < NT; nt++) {
            int gch  = n0 + nt * 32 + l31;
            int c    = gch >> 1, half = gch & 1;
            float sc = aff[2 * c], sh = aff[2 * c + 1];
            const float* xp = xb + (size_t)c * HWc;
            #pragma unroll
            for (int t = 0; t < 8; t++) {
                int reg0 = 2 * t;
                int row  = (reg0 & 3) + 8 * (reg0 >> 2) + 4 * kg;
                int p    = p0 + wv * 32 + row;
                float oi = acc[nt][reg0];
                float oj = acc[nt][reg0 + 1];
                int q  = half * (HWc >> 1) + (p >> 1);
                int qi = q / W, qj = q % W;
                float ci_ = fminf(fmaxf(oi + (float)qi, 0.f), (float)(H - 1));
                float cj_ = fminf(fmaxf(oj + (float)qj, 0.f), (float)(W - 1));
                float i0f = floorf(ci_), j0f = floorf(cj_);
                int i0 = (int)i0f, i1 = (int)ceilf(ci_);
                int j0 = (int)j0f, j1 = (int)ceilf(cj_);
                float v00 = xp[i0 * W + j0];
                float v10 = xp[i1 * W + j0];
                float v01 = xp[i0 * W + j1];
                float v11 = xp[i1 * W + j1];
                float di = ci_ - i0f, dj = cj_ - j0f;
                float top = v00 + di * (v10 - v00);
                float bot = v01 + di * (v11 - v01);
                float res = top + dj * (bot - top);
                out[((size_t)b * CIN + c) * HWc + q] = res * sc + sh;
            }
        }
    }
    if (BREL) {
        #pragma unroll
        for (int nt = 0; nt < NT; nt++) {
            int co = n0 + nt * 32 + l31;
            float bv = bias[co];
            #pragma unroll
            for (int reg = 0; reg < 16; reg++) {
                int row = (reg & 3) + 8 * (reg >> 2) + 4 * kg;
                int p   = p0 + wv * 32 + row;
                out[((size_t)b * CO + co) * HWc + p] = fmaxf(acc[nt][reg] + bv, 0.f);
            }
        }
    }
}

// ---------------------------------------------------------------------------
// Vector direct 3x3 conv (conv11 and the stride-2 convs).
// ---------------------------------------------------------------------------
template<int STRIDE>
__global__ __launch_bounds__(256) void conv3x3_kernel(
    const float* __restrict__ in, const float* __restrict__ wgt,
    const float* __restrict__ bias, float* __restrict__ out,
    int B, int Cin, int H, int W, int Cout, int Ho, int Wo, int do_relu)
{
    constexpr int TILE = 28;
    constexpr int PR   = (TILE - 1) * STRIDE + 3;
    constexpr int PADW = (STRIDE == 1) ? 32 : 60;
    constexpr int COPB = 8;
    constexpr int RW   = STRIDE + 3;
    __shared__ float patch[PR * PADW];

    int cpg  = Cout / COPB;
    int bz   = blockIdx.z;
    int cog  = bz % cpg;
    int b    = bz / cpg;
    int co0  = cog * COPB;
    int tid  = threadIdx.x;
    int oy0  = blockIdx.y * TILE, ox0 = blockIdx.x * TILE;
    int iy0  = oy0 * STRIDE - 1,  ix0 = ox0 * STRIDE - 1;

    bool active = tid < 196;
    int ty = tid / 14, tx = tid % 14;
    int py = oy0 + 2 * ty, px = ox0 + 2 * tx;

    float acc[COPB][4];
    #pragma unroll
    for (int i = 0; i < COPB; i++) {
        float bv = bias ? bias[co0 + i] : 0.f;
        #pragma unroll
        for (int j = 0; j < 4; j++) acc[i][j] = bv;
    }

    const size_t HW = (size_t)H * W;
    for (int ci = 0; ci < Cin; ci++) {
        const float* ip = in + ((size_t)b * Cin + ci) * HW;
        for (int t = tid; t < PR * PADW; t += 256) {
            int sy = t / PADW, sx = t % PADW;
            float v = 0.f;
            int gy = iy0 + sy, gx = ix0 + sx;
            if (sx < PR && gy >= 0 && gy < H && gx >= 0 && gx < W)
                v = ip[(size_t)gy * W + gx];
            patch[t] = v;
        }
        __syncthreads();
        if (active) {
            float r[RW][RW];
            #pragma unroll
            for (int rr = 0; rr < RW; rr++) {
                int rowbase = (2 * ty * STRIDE + rr) * PADW + 2 * tx * STRIDE;
                if (STRIDE == 1) {
                    float2 a = *(const float2*)&patch[rowbase];
                    float2 c = *(const float2*)&patch[rowbase + 2];
                    r[rr][0] = a.x; r[rr][1] = a.y; r[rr][2] = c.x; r[rr][3] = c.y;
                } else {
                    float4 a = *(const float4*)&patch[rowbase];
                    r[rr][0] = a.x; r[rr][1] = a.y; r[rr][2] = a.z; r[rr][3] = a.w;
                    r[rr][4] = patch[rowbase + 4];
                }
            }
            const float* wb = wgt + ((size_t)co0 * Cin + ci) * 9;
            #pragma unroll
            for (int i = 0; i < COPB; i++) {
                const float* wp = wb + (size_t)i * Cin * 9;
                #pragma unroll
                for (int ki = 0; ki < 3; ki++)
                    #pragma unroll
                    for (int kj = 0; kj < 3; kj++) {
                        float w = wp[ki * 3 + kj];
                        acc[i][0] = fmaf(r[ki][kj],                   w, acc[i][0]);
                        acc[i][1] = fmaf(r[ki][kj + STRIDE],          w, acc[i][1]);
                        acc[i][2] = fmaf(r[ki + STRIDE][kj],          w, acc[i][2]);
                        acc[i][3] = fmaf(r[ki + STRIDE][kj + STRIDE], w, acc[i][3]);
                    }
            }
        }
        __syncthreads();
    }
    if (active) {
        #pragma unroll
        for (int rr = 0; rr < 2; rr++) {
            #pragma unroll
            for (int cc = 0; cc < 2; cc++) {
                int oy = py + rr, ox = px + cc;
                if (oy < Ho && ox < Wo) {
                    #pragma unroll
                    for (int i = 0; i < COPB; i++) {
                        float v = acc[i][rr * 2 + cc];
                        if (do_relu) v = fmaxf(v, 0.f);
                        out[(((size_t)b * Cout + co0 + i) * Ho + oy) * Wo + ox] = v;
                    }
                }
            }
        }
    }
}

// ---------------------------------------------------------------------------
__global__ __launch_bounds__(256) void bn_stats_kernel(
    const float* __restrict__ x, float* __restrict__ stats,
    int B, int C, int HW)
{
    int c = blockIdx.x;
    long long cnt = (long long)B * HW;
    long long step = (long long)gridDim.y * blockDim.x;
    float s = 0.f, s2 = 0.f;
    for (long long t = (long long)blockIdx.y * blockDim.x + threadIdx.x; t < cnt; t += step) {
        int b  = (int)(t / HW);
        int sp = (int)(t % HW);
        float v = x[((size_t)b * C + c) * (size_t)HW + sp];
        s += v; s2 += v * v;
    }
    for (int off = 32; off; off >>= 1) {
        s  += __shfl_down(s, off);
        s2 += __shfl_down(s2, off);
    }
    __shared__ float ls[4], ls2[4];
    int wave = threadIdx.x >> 6, lane = threadIdx.x & 63;
    if (lane == 0) { ls[wave] = s; ls2[wave] = s2; }
    __syncthreads();
    if (threadIdx.x == 0) {
        float ts = 0.f, ts2 = 0.f;
        for (int i = 0; i < 4; i++) { ts += ls[i]; ts2 += ls2[i]; }
        atomicAdd(&stats[c], ts);
        atomicAdd(&stats[C + c], ts2);
    }
}

// ---------------------------------------------------------------------------
__global__ void zero_kernel(float* __restrict__ p, int n)
{
    int i = blockIdx.x * blockDim.x + threadIdx.x;
    if (i < n) p[i] = 0.f;
}

// ---------------------------------------------------------------------------
__global__ __launch_bounds__(256) void pool_kernel(
    const float* __restrict__ x, const float* __restrict__ stats,
    const float* __restrict__ g, const float* __restrict__ be,
    float inv_cnt, float* __restrict__ out, int C, int HW)
{
    int bc = blockIdx.x;
    int c  = bc % C;
    const float* xp = x + (size_t)bc * HW;
    float s = 0.f;
    for (int i = threadIdx.x; i < HW; i += blockDim.x) s += xp[i];
    for (int off = 32; off; off >>= 1) s += __shfl_down(s, off);
    __shared__ float ls[4];
    int wave = threadIdx.x >> 6, lane = threadIdx.x & 63;
    if (lane == 0) ls[wave] = s;
    __syncthreads();
    if (threadIdx.x == 0) {
        float t = 0.f;
        for (int i = 0; i < 4; i++) t += ls[i];
        float mean = t / (float)HW;
        float m  = stats[c] * inv_cnt;
        float vv = stats[C + c] * inv_cnt - m * m;
        float sc = g[c] / sqrtf(vv + BN_EPS);
        float sh = be[c] - m * sc;
        out[bc] = mean * sc + sh;
    }
}

// ---------------------------------------------------------------------------
__global__ __launch_bounds__(128) void fc_softmax_kernel(
    const float* __restrict__ pool, const float* __restrict__ wfc,
    const float* __restrict__ bfc, float* __restrict__ out)
{
    int b = blockIdx.x;
    __shared__ float row[128];
    __shared__ float logits[10];
    int tid = threadIdx.x;
    row[tid] = pool[b * 128 + tid];
    __syncthreads();
    if (tid < 10) {
        float s = bfc[tid];
        for (int k = 0; k < 128; k++) s = fmaf(row[k], wfc[tid * 128 + k], s);
        logits[tid] = s;
    }
    __syncthreads();
    if (tid < 10) {
        float mx = logits[0];
        for (int i = 1; i < 10; i++) mx = fmaxf(mx, logits[i]);
        float sum = 0.f;
        for (int i = 0; i < 10; i++) sum += expf(logits[i] - mx);
        out[b * 10 + tid] = expf(logits[tid] - mx) / sum;
    }
}

// ---------------------------------------------------------------------------
extern "C" void kernel_launch(void* const* d_in, const int* in_sizes, int n_in,
                              void* d_out, int out_size, void* d_ws, size_t ws_size,
                              hipStream_t stream)
{
    const float* x      = (const float*)d_in[0];
    const float* w11    = (const float*)d_in[1];
    const float* b11    = (const float*)d_in[2];
    const float* g11    = (const float*)d_in[3];
    const float* be11   = (const float*)d_in[4];
    const float* woff12 = (const float*)d_in[5];
    const float* w12    = (const float*)d_in[6];
    const float* b12    = (const float*)d_in[7];
    const float* g12    = (const float*)d_in[8];
    const float* be12   = (const float*)d_in[9];
    const float* woff21 = (const float*)d_in[10];
    const float* w21    = (const float*)d_in[11];
    const float* b21    = (const float*)d_in[12];
    const float* g21    = (const float*)d_in[13];
    const float* be21   = (const float*)d_in[14];
    const float* woff22 = (const float*)d_in[15];
    const float* w22    = (const float*)d_in[16];
    const float* b22    = (const float*)d_in[17];
    const float* g22    = (const float*)d_in[18];
    const float* be22   = (const float*)d_in[19];
    const float* wfc    = (const float*)d_in[20];
    const float* bfc    = (const float*)d_in[21];
    float* out = (float*)d_out;

    float* ws    = (float*)d_ws;
    const size_t SZ_B = 25690112;   // 64*32*112*112 = 64*128*56*56 floats
    float* Bbuf  = ws;
    float* Cbuf  = Bbuf + SZ_B;
    float* stats = Cbuf + SZ_B;      // 512
    float* aff   = stats + 512;      // 512
    float* poolb = aff + 512;        // 8192
    ushort_t* warena = (ushort_t*)(poolb + 8192);
    const size_t W12 = 9 * 64 * 32;
    const size_t W21 = 9 * 128 * 64;
    const size_t W22 = 9 * 256 * 128;
    ushort_t* wp12h = warena;          ushort_t* wp12l = wp12h + W12;
    ushort_t* wp21h = wp12l + W12;     ushort_t* wp21l = wp21h + W21;
    ushort_t* wc21h = wp21l + W21;     ushort_t* wc21l = wc21h + W21;
    ushort_t* wp22h = wc21l + W21;     ushort_t* wp22l = wp22h + W22;

    const int B = 64;

    prep_w_kernel<<<(9 * 64 * 32 + 255) / 256, 256, 0, stream>>>(woff12, wp12h, wp12l, 64, 32);
    prep_w_kernel<<<(9 * 128 * 64 + 255) / 256, 256, 0, stream>>>(woff21, wp21h, wp21l, 128, 64);
    prep_w_kernel<<<(9 * 128 * 64 + 255) / 256, 256, 0, stream>>>(w21, wc21h, wc21l, 128, 64);
    prep_w_kernel<<<(9 * 256 * 128 + 255) / 256, 256, 0, stream>>>(woff22, wp22h, wp22l, 256, 128);

    // ---- Layer 1.1: conv(1->32, s1)+relu -> Bbuf raw; stats; finalize ----
    conv3x3_kernel<1><<<dim3(4, 4, B * (32 / 8)), 256, 0, stream>>>(
        x, w11, b11, Bbuf, B, 1, 112, 112, 32, 112, 112, 1);
    zero_kernel<<<2, 256, 0, stream>>>(stats, 512);
    bn_stats_kernel<<<dim3(32, 64), 256, 0, stream>>>(Bbuf, stats, B, 32, 12544);
    bn_finalize_kernel<<<1, 256, 0, stream>>>(stats, g11, be11, 1.f / (64.f * 12544.f), aff, 32);

    // ---- deform12 (MFMA, single-buf): BN(1.1)-fused offconv + resample ----
    mfma_conv_kernel<112, 112, 32, 64, 2, true, true, false, false>
        <<<dim3(196, B, 1), 128, 0, stream>>>(Bbuf, wp12h, wp12l, aff, nullptr, Cbuf);

    // ---- Layer 1.2: conv(32->64, s2)+relu -> Bbuf raw; stats; finalize ----
    conv3x3_kernel<2><<<dim3(2, 2, B * (64 / 8)), 256, 0, stream>>>(
        Cbuf, w12, b12, Bbuf, B, 32, 112, 112, 64, 56, 56, 1);
    zero_kernel<<<2, 256, 0, stream>>>(stats, 512);
    bn_stats_kernel<<<dim3(64, 64), 256, 0, stream>>>(Bbuf, stats, B, 64, 3136);
    bn_finalize_kernel<<<1, 256, 0, stream>>>(stats, g12, be12, 1.f / (64.f * 3136.f), aff, 64);

    // ---- deform21 (MFMA, dbuf): BN(1.2)-fused offconv + resample ----
    mfma_conv_kernel<56, 56, 64, 128, 4, true, true, false, true>
        <<<dim3(49, B, 1), 128, 0, stream>>>(Bbuf, wp21h, wp21l, aff, nullptr, Cbuf);

    // ---- Layer 2.1 (MFMA, dbuf): conv(64->128, s1)+bias+relu -> Bbuf ----
    mfma_conv_kernel<56, 56, 64, 128, 4, false, false, true, true>
        <<<dim3(49, B, 1), 128, 0, stream>>>(Cbuf, wc21h, wc21l, nullptr, b21, Bbuf);
    zero_kernel<<<2, 256, 0, stream>>>(stats, 512);
    bn_stats_kernel<<<dim3(128, 64), 256, 0, stream>>>(Bbuf, stats, B, 128, 3136);
    bn_finalize_kernel<<<1, 256, 0, stream>>>(stats, g21, be21, 1.f / (64.f * 3136.f), aff, 128);

    // ---- deform22 (MFMA, dbuf): BN(2.1)-fused offconv + resample ----
    mfma_conv_kernel<56, 56, 128, 256, 4, true, true, false, true>
        <<<dim3(49, B, 2), 128, 0, stream>>>(Bbuf, wp22h, wp22l, aff, nullptr, Cbuf);

    // ---- Layer 2.2: conv(128->128, s2)+relu -> Bbuf raw; stats ----
    conv3x3_kernel<2><<<dim3(1, 1, B * (128 / 8)), 256, 0, stream>>>(
        Cbuf, w22, b22, Bbuf, B, 128, 56, 56, 128, 28, 28, 1);
    zero_kernel<<<2, 256, 0, stream>>>(stats, 512);
    bn_stats_kernel<<<dim3(128, 64), 256, 0, stream>>>(Bbuf, stats, B, 128, 784);

    // ---- Pool (BN(2.2) fused) + FC + softmax ----
    pool_kernel<<<B * 128, 256, 0, stream>>>(
        Bbuf, stats, g22, be22, 1.f / (64.f * 784.f), poolb, 128, 784);
    fc_softmax_kernel<<<B, 128, 0, stream>>>(poolb, wfc, bfc, out);
}

// Round 8
// 3811.324 us; speedup vs baseline: 4.0568x; 1.0156x over previous
//
#include <hip/hip_runtime.h>
#include <math.h>

#define BN_EPS 1e-5f

typedef unsigned short ushort_t;
typedef __attribute__((ext_vector_type(8))) short short8;     // 8 bf16 (4 VGPR)
typedef __attribute__((ext_vector_type(16))) float floatx16;  // MFMA 32x32 acc

// Split fp32 into bf16 hi (bit-truncate, exact) + bf16 lo (truncated remainder).
__device__ __forceinline__ void split_bf16(float v, ushort_t& h, ushort_t& l) {
    unsigned u = __float_as_uint(v);
    float fhi = __uint_as_float(u & 0xFFFF0000u);
    h = (ushort_t)(u >> 16);
    l = (ushort_t)(__float_as_uint(v - fhi) >> 16);
}

// ---------------------------------------------------------------------------
// Weight prep: OIHW fp32 -> [tap][O][I] bf16 hi/lo (B-fragment-ready).
// ---------------------------------------------------------------------------
__global__ __launch_bounds__(256) void prep_w_kernel(
    const float* __restrict__ w, ushort_t* __restrict__ hi,
    ushort_t* __restrict__ lo, int O, int I)
{
    int idx = blockIdx.x * 256 + threadIdx.x;
    int n = 9 * O * I;
    if (idx >= n) return;
    int i = idx % I;
    int rest = idx / I;
    int o = rest % O;
    int t = rest / O;
    float v = w[((size_t)o * I + i) * 9 + t];
    split_bf16(v, hi[idx], lo[idx]);
}

// ---------------------------------------------------------------------------
__global__ void bn_finalize_kernel(
    const float* __restrict__ stats, const float* __restrict__ g,
    const float* __restrict__ be, float inv_cnt, float* __restrict__ aff, int C)
{
    int c = threadIdx.x;
    if (c < C) {
        float m  = stats[c] * inv_cnt;
        float vv = stats[C + c] * inv_cnt - m * m;
        float sc = g[c] / sqrtf(vv + BN_EPS);
        aff[2 * c]     = sc;
        aff[2 * c + 1] = be[c] - m * sc;
    }
}

// ---------------------------------------------------------------------------
// MFMA 3x3 conv (stride 1), split-bf16 fp32 emulation (Ah*Bh + Ah*Bl + Al*Bh).
// Block = 128 threads (2 waves); wave = one 32-pixel M-tile, NT 32-ch N-tiles.
// __launch_bounds__(128,2): VGPR cap 256 so prefetch regs stay live across
// the MFMA phase (round-7's 112-VGPR cap sank the prefetch loads and
// defeated the pipeline).
// mfma_phase is software-pipelined: tap t+1's B-frag global loads and A-frag
// ds_reads issue before tap t's 12-MFMA burst (ping-pong register sets).
// DBUF: chunk k+1's staging loads issue before mfma_phase(k), LDS write
// after, one barrier per chunk.
// Epilogues (verified exact rounds 3-7): DEFORM pair-in-lane remap + BN;
// BREL bias+relu store.
// ---------------------------------------------------------------------------
template<int W, int H, int CIN, int CO, int NT, bool DEFORM, bool BNIN, bool BREL, bool DBUF>
__global__ __launch_bounds__(128, 2) void mfma_conv_kernel(
    const float* __restrict__ x, const ushort_t* __restrict__ wh,
    const ushort_t* __restrict__ wl, const float* __restrict__ aff,
    const float* __restrict__ bias, float* __restrict__ out)
{
    constexpr int PADC = W + 2;
    constexpr int PSZ  = 4 * PADC * 16;      // ushorts per buffer
    constexpr int NB   = DBUF ? 2 : 1;
    constexpr int NC4  = W / 4;
    constexpr int NIT  = 8 * 4 * NC4;        // cipair x row x c4 items per chunk
    constexpr int NCH  = CIN / 16;
    constexpr int PF   = (NIT + 127) / 128;  // staging regs per array
    __shared__ __align__(16) ushort_t patch_h[NB][PSZ];
    __shared__ __align__(16) ushort_t patch_l[NB][PSZ];

    const int tid  = threadIdx.x;
    const int wv   = tid >> 6;
    const int lane = tid & 63;
    const int l31  = lane & 31;
    const int kg   = lane >> 5;
    const int p0   = blockIdx.x * 64;
    const int b    = blockIdx.y;
    const int n0   = blockIdx.z * (NT * 32);
    const int HWc  = H * W;

    const int mp = p0 + wv * 32 + l31;
    const int py = mp / W, px = mp % W;
    const int r0 = p0 / W;
    const int abase = ((py - r0) * PADC + px) * 16 + kg * 8;

    const float* xb = x + (size_t)b * CIN * HWc;

    // ---- zero halo cols (always OOB -> 0 for every chunk) ----
    for (int t = tid; t < NB * 128; t += 128) {
        int bb = t >> 7, r = (t >> 5) & 3, side = (t >> 4) & 1, ci = t & 15;
        int col = side ? (PADC - 1) : 0;
        int slot = (r * PADC + col) * 16 + ci;
        patch_h[bb][slot] = 0;
        patch_l[bb][slot] = 0;
    }

    floatx16 acc[NT];
    #pragma unroll
    for (int nt = 0; nt < NT; nt++)
        #pragma unroll
        for (int i = 0; i < 16; i++) acc[nt][i] = 0.f;

    // per-nt lane-fixed weight offsets (tap/chunk added per use)
    size_t wofs[NT];
    #pragma unroll
    for (int nt = 0; nt < NT; nt++)
        wofs[nt] = (size_t)(n0 + nt * 32 + l31) * CIN + kg * 8;

    // fused stage (load + BN + split + LDS write) for chunk ci0 into buf bb
    auto stage_fused = [&](int ci0, int bb) {
        for (int t = tid; t < NIT; t += 128) {
            int cp = t & 7, row = (t >> 3) & 3, c4 = t >> 5;
            int ci = 2 * cp;
            int gy = r0 - 1 + row, gx = 4 * c4;
            float4 v0 = {0.f, 0.f, 0.f, 0.f}, v1 = v0;
            if (gy >= 0 && gy < H) {
                v0 = *(const float4*)(xb + (size_t)(ci0 + ci) * HWc + gy * W + gx);
                v1 = *(const float4*)(xb + (size_t)(ci0 + ci + 1) * HWc + gy * W + gx);
                if (BNIN) {
                    float sc0 = aff[2 * (ci0 + ci)],     sh0 = aff[2 * (ci0 + ci) + 1];
                    float sc1 = aff[2 * (ci0 + ci) + 2], sh1 = aff[2 * (ci0 + ci) + 3];
                    v0.x = fmaf(v0.x, sc0, sh0); v0.y = fmaf(v0.y, sc0, sh0);
                    v0.z = fmaf(v0.z, sc0, sh0); v0.w = fmaf(v0.w, sc0, sh0);
                    v1.x = fmaf(v1.x, sc1, sh1); v1.y = fmaf(v1.y, sc1, sh1);
                    v1.z = fmaf(v1.z, sc1, sh1); v1.w = fmaf(v1.w, sc1, sh1);
                }
            }
            int base = (row * PADC + gx + 1) * 16 + ci;
            const float e0[4] = {v0.x, v0.y, v0.z, v0.w};
            const float e1[4] = {v1.x, v1.y, v1.z, v1.w};
            #pragma unroll
            for (int j = 0; j < 4; j++) {
                ushort_t h0, l0, h1, l1;
                split_bf16(e0[j], h0, l0);
                split_bf16(e1[j], h1, l1);
                *(ushort2*)&patch_h[bb][base + 16 * j] = make_ushort2(h0, h1);
                *(ushort2*)&patch_l[bb][base + 16 * j] = make_ushort2(l0, l1);
            }
        }
    };

    // software-pipelined MFMA phase: tap t+1 loads issued before tap t MFMAs
    auto mfma_phase = [&](int bb, int ci0) {
        const ushort_t* ph = patch_h[bb];
        const ushort_t* pl = patch_l[bb];
        short8 bh[2][NT], bl[2][NT];
        short8 ah[2], al[2];
        #pragma unroll
        for (int nt = 0; nt < NT; nt++) {
            bh[0][nt] = *(const short8*)(wh + wofs[nt] + ci0);
            bl[0][nt] = *(const short8*)(wl + wofs[nt] + ci0);
        }
        ah[0] = *(const short8*)&ph[abase];
        al[0] = *(const short8*)&pl[abase];
        #pragma unroll
        for (int tap = 0; tap < 9; tap++) {
            const int cur = tap & 1, nxt = cur ^ 1;
            if (tap < 8) {
                const size_t tofs = (size_t)(tap + 1) * CO * CIN + ci0;
                #pragma unroll
                for (int nt = 0; nt < NT; nt++) {
                    bh[nxt][nt] = *(const short8*)(wh + wofs[nt] + tofs);
                    bl[nxt][nt] = *(const short8*)(wl + wofs[nt] + tofs);
                }
                const int ki = (tap + 1) / 3, kj = (tap + 1) % 3;
                const int aoff = abase + (ki * PADC + kj) * 16;
                ah[nxt] = *(const short8*)&ph[aoff];
                al[nxt] = *(const short8*)&pl[aoff];
            }
            #pragma unroll
            for (int nt = 0; nt < NT; nt++) {
                acc[nt] = __builtin_amdgcn_mfma_f32_32x32x16_bf16(ah[cur], bh[cur][nt], acc[nt], 0, 0, 0);
                acc[nt] = __builtin_amdgcn_mfma_f32_32x32x16_bf16(ah[cur], bl[cur][nt], acc[nt], 0, 0, 0);
                acc[nt] = __builtin_amdgcn_mfma_f32_32x32x16_bf16(al[cur], bh[cur][nt], acc[nt], 0, 0, 0);
            }
        }
    };

    // ---- prologue: stage chunk 0 ----
    stage_fused(0, 0);
    __syncthreads();

    for (int ch = 0; ch < NCH; ch++) {
        if constexpr (DBUF) {
            const int bb = ch & 1;
            const bool pfv = (ch + 1 < NCH);
            float4 pa[PF], pb[PF];
            if (pfv) {
                const int ci0n = (ch + 1) * 16;
                int k = 0;
                for (int t = tid; t < NIT; t += 128, k++) {
                    int cp = t & 7, row = (t >> 3) & 3, c4 = t >> 5;
                    int ci = 2 * cp;
                    int gy = r0 - 1 + row, gx = 4 * c4;
                    float4 v0 = {0.f, 0.f, 0.f, 0.f}, v1 = v0;
                    if (gy >= 0 && gy < H) {
                        v0 = *(const float4*)(xb + (size_t)(ci0n + ci) * HWc + gy * W + gx);
                        v1 = *(const float4*)(xb + (size_t)(ci0n + ci + 1) * HWc + gy * W + gx);
                        if (BNIN) {
                            float sc0 = aff[2 * (ci0n + ci)],     sh0 = aff[2 * (ci0n + ci) + 1];
                            float sc1 = aff[2 * (ci0n + ci) + 2], sh1 = aff[2 * (ci0n + ci) + 3];
                            v0.x = fmaf(v0.x, sc0, sh0); v0.y = fmaf(v0.y, sc0, sh0);
                            v0.z = fmaf(v0.z, sc0, sh0); v0.w = fmaf(v0.w, sc0, sh0);
                            v1.x = fmaf(v1.x, sc1, sh1); v1.y = fmaf(v1.y, sc1, sh1);
                            v1.z = fmaf(v1.z, sc1, sh1); v1.w = fmaf(v1.w, sc1, sh1);
                        }
                    }
                    pa[k] = v0; pb[k] = v1;
                }
            }
            mfma_phase(bb, ch * 16);
            if (pfv) {
                const int nb2 = (ch + 1) & 1;
                int k = 0;
                for (int t = tid; t < NIT; t += 128, k++) {
                    int cp = t & 7, row = (t >> 3) & 3, c4 = t >> 5;
                    int ci = 2 * cp;
                    int gx = 4 * c4;
                    int base = (row * PADC + gx + 1) * 16 + ci;
                    const float e0[4] = {pa[k].x, pa[k].y, pa[k].z, pa[k].w};
                    const float e1[4] = {pb[k].x, pb[k].y, pb[k].z, pb[k].w};
                    #pragma unroll
                    for (int j = 0; j < 4; j++) {
                        ushort_t h0, l0, h1, l1;
                        split_bf16(e0[j], h0, l0);
                        split_bf16(e1[j], h1, l1);
                        *(ushort2*)&patch_h[nb2][base + 16 * j] = make_ushort2(h0, h1);
                        *(ushort2*)&patch_l[nb2][base + 16 * j] = make_ushort2(l0, l1);
                    }
                }
            }
            __syncthreads();
        } else {
            mfma_phase(0, ch * 16);
            if (ch + 1 < NCH) {
                __syncthreads();
                stage_fused((ch + 1) * 16, 0);
                __syncthreads();
            }
        }
    }

    if (DEFORM) {
        #pragma unroll
        for (int nt = 0; nt < NT; nt++) {
            int gch  = n0 + nt * 32 + l31;
            int c    = gch >> 1, half = gch & 1;
            float sc = aff[2 * c], sh = aff[2 * c + 1];
            const float* xp = xb + (size_t)c * HWc;
            #pragma unroll
            for (int t = 0; t < 8; t++) {
                int reg0 = 2 * t;
                int row  = (reg0 & 3) + 8 * (reg0 >> 2) + 4 * kg;
                int p    = p0 + wv * 32 + row;
                float oi = acc[nt][reg0];
                float oj = acc[nt][reg0 + 1];
                int q  = half * (HWc >> 1) + (p >> 1);
                int qi = q / W, qj = q % W;
                float ci_ = fminf(fmaxf(oi + (float)qi, 0.f), (float)(H - 1));
                float cj_ = fminf(fmaxf(oj + (float)qj, 0.f), (float)(W - 1));
                float i0f = floorf(ci_), j0f = floorf(cj_);
                int i0 = (int)i0f, i1 = (int)ceilf(ci_);
                int j0 = (int)j0f, j1 = (int)ceilf(cj_);
                float v00 = xp[i0 * W + j0];
                float v10 = xp[i1 * W + j0];
                float v01 = xp[i0 * W + j1];
                float v11 = xp[i1 * W + j1];
                float di = ci_ - i0f, dj = cj_ - j0f;
                float top = v00 + di * (v10 - v00);
                float bot = v01 + di * (v11 - v01);
                float res = top + dj * (bot - top);
                out[((size_t)b * CIN + c) * HWc + q] = res * sc + sh;
            }
        }
    }
    if (BREL) {
        #pragma unroll
        for (int nt = 0; nt < NT; nt++) {
            int co = n0 + nt * 32 + l31;
            float bv = bias[co];
            #pragma unroll
            for (int reg = 0; reg < 16; reg++) {
                int row = (reg & 3) + 8 * (reg >> 2) + 4 * kg;
                int p   = p0 + wv * 32 + row;
                out[((size_t)b * CO + co) * HWc + p] = fmaxf(acc[nt][reg] + bv, 0.f);
            }
        }
    }
}

// ---------------------------------------------------------------------------
// Vector direct 3x3 conv (conv11 and the stride-2 convs).
// ---------------------------------------------------------------------------
template<int STRIDE>
__global__ __launch_bounds__(256) void conv3x3_kernel(
    const float* __restrict__ in, const float* __restrict__ wgt,
    const float* __restrict__ bias, float* __restrict__ out,
    int B, int Cin, int H, int W, int Cout, int Ho, int Wo, int do_relu)
{
    constexpr int TILE = 28;
    constexpr int PR   = (TILE - 1) * STRIDE + 3;
    constexpr int PADW = (STRIDE == 1) ? 32 : 60;
    constexpr int COPB = 8;
    constexpr int RW   = STRIDE + 3;
    __shared__ float patch[PR * PADW];

    int cpg  = Cout / COPB;
    int bz   = blockIdx.z;
    int cog  = bz % cpg;
    int b    = bz / cpg;
    int co0  = cog * COPB;
    int tid  = threadIdx.x;
    int oy0  = blockIdx.y * TILE, ox0 = blockIdx.x * TILE;
    int iy0  = oy0 * STRIDE - 1,  ix0 = ox0 * STRIDE - 1;

    bool active = tid < 196;
    int ty = tid / 14, tx = tid % 14;
    int py = oy0 + 2 * ty, px = ox0 + 2 * tx;

    float acc[COPB][4];
    #pragma unroll
    for (int i = 0; i < COPB; i++) {
        float bv = bias ? bias[co0 + i] : 0.f;
        #pragma unroll
        for (int j = 0; j < 4; j++) acc[i][j] = bv;
    }

    const size_t HW = (size_t)H * W;
    for (int ci = 0; ci < Cin; ci++) {
        const float* ip = in + ((size_t)b * Cin + ci) * HW;
        for (int t = tid; t < PR * PADW; t += 256) {
            int sy = t / PADW, sx = t % PADW;
            float v = 0.f;
            int gy = iy0 + sy, gx = ix0 + sx;
            if (sx < PR && gy >= 0 && gy < H && gx >= 0 && gx < W)
                v = ip[(size_t)gy * W + gx];
            patch[t] = v;
        }
        __syncthreads();
        if (active) {
            float r[RW][RW];
            #pragma unroll
            for (int rr = 0; rr < RW; rr++) {
                int rowbase = (2 * ty * STRIDE + rr) * PADW + 2 * tx * STRIDE;
                if (STRIDE == 1) {
                    float2 a = *(const float2*)&patch[rowbase];
                    float2 c = *(const float2*)&patch[rowbase + 2];
                    r[rr][0] = a.x; r[rr][1] = a.y; r[rr][2] = c.x; r[rr][3] = c.y;
                } else {
                    float4 a = *(const float4*)&patch[rowbase];
                    r[rr][0] = a.x; r[rr][1] = a.y; r[rr][2] = a.z; r[rr][3] = a.w;
                    r[rr][4] = patch[rowbase + 4];
                }
            }
            const float* wb = wgt + ((size_t)co0 * Cin + ci) * 9;
            #pragma unroll
            for (int i = 0; i < COPB; i++) {
                const float* wp = wb + (size_t)i * Cin * 9;
                #pragma unroll
                for (int ki = 0; ki < 3; ki++)
                    #pragma unroll
                    for (int kj = 0; kj < 3; kj++) {
                        float w = wp[ki * 3 + kj];
                        acc[i][0] = fmaf(r[ki][kj],                   w, acc[i][0]);
                        acc[i][1] = fmaf(r[ki][kj + STRIDE],          w, acc[i][1]);
                        acc[i][2] = fmaf(r[ki + STRIDE][kj],          w, acc[i][2]);
                        acc[i][3] = fmaf(r[ki + STRIDE][kj + STRIDE], w, acc[i][3]);
                    }
            }
        }
        __syncthreads();
    }
    if (active) {
        #pragma unroll
        for (int rr = 0; rr < 2; rr++) {
            #pragma unroll
            for (int cc = 0; cc < 2; cc++) {
                int oy = py + rr, ox = px + cc;
                if (oy < Ho && ox < Wo) {
                    #pragma unroll
                    for (int i = 0; i < COPB; i++) {
                        float v = acc[i][rr * 2 + cc];
                        if (do_relu) v = fmaxf(v, 0.f);
                        out[(((size_t)b * Cout + co0 + i) * Ho + oy) * Wo + ox] = v;
                    }
                }
            }
        }
    }
}

// ---------------------------------------------------------------------------
__global__ __launch_bounds__(256) void bn_stats_kernel(
    const float* __restrict__ x, float* __restrict__ stats,
    int B, int C, int HW)
{
    int c = blockIdx.x;
    long long cnt = (long long)B * HW;
    long long step = (long long)gridDim.y * blockDim.x;
    float s = 0.f, s2 = 0.f;
    for (long long t = (long long)blockIdx.y * blockDim.x + threadIdx.x; t < cnt; t += step) {
        int b  = (int)(t / HW);
        int sp = (int)(t % HW);
        float v = x[((size_t)b * C + c) * (size_t)HW + sp];
        s += v; s2 += v * v;
    }
    for (int off = 32; off; off >>= 1) {
        s  += __shfl_down(s, off);
        s2 += __shfl_down(s2, off);
    }
    __shared__ float ls[4], ls2[4];
    int wave = threadIdx.x >> 6, lane = threadIdx.x & 63;
    if (lane == 0) { ls[wave] = s; ls2[wave] = s2; }
    __syncthreads();
    if (threadIdx.x == 0) {
        float ts = 0.f, ts2 = 0.f;
        for (int i = 0; i < 4; i++) { ts += ls[i]; ts2 += ls2[i]; }
        atomicAdd(&stats[c], ts);
        atomicAdd(&stats[C + c], ts2);
    }
}

// ---------------------------------------------------------------------------
__global__ void zero_kernel(float* __restrict__ p, int n)
{
    int i = blockIdx.x * blockDim.x + threadIdx.x;
    if (i < n) p[i] = 0.f;
}

// ---------------------------------------------------------------------------
__global__ __launch_bounds__(256) void pool_kernel(
    const float* __restrict__ x, const float* __restrict__ stats,
    const float* __restrict__ g, const float* __restrict__ be,
    float inv_cnt, float* __restrict__ out, int C, int HW)
{
    int bc = blockIdx.x;
    int c  = bc % C;
    const float* xp = x + (size_t)bc * HW;
    float s = 0.f;
    for (int i = threadIdx.x; i < HW; i += blockDim.x) s += xp[i];
    for (int off = 32; off; off >>= 1) s += __shfl_down(s, off);
    __shared__ float ls[4];
    int wave = threadIdx.x >> 6, lane = threadIdx.x & 63;
    if (lane == 0) ls[wave] = s;
    __syncthreads();
    if (threadIdx.x == 0) {
        float t = 0.f;
        for (int i = 0; i < 4; i++) t += ls[i];
        float mean = t / (float)HW;
        float m  = stats[c] * inv_cnt;
        float vv = stats[C + c] * inv_cnt - m * m;
        float sc = g[c] / sqrtf(vv + BN_EPS);
        float sh = be[c] - m * sc;
        out[bc] = mean * sc + sh;
    }
}

// ---------------------------------------------------------------------------
__global__ __launch_bounds__(128) void fc_softmax_kernel(
    const float* __restrict__ pool, const float* __restrict__ wfc,
    const float* __restrict__ bfc, float* __restrict__ out)
{
    int b = blockIdx.x;
    __shared__ float row[128];
    __shared__ float logits[10];
    int tid = threadIdx.x;
    row[tid] = pool[b * 128 + tid];
    __syncthreads();
    if (tid < 10) {
        float s = bfc[tid];
        for (int k = 0; k < 128; k++) s = fmaf(row[k], wfc[tid * 128 + k], s);
        logits[tid] = s;
    }
    __syncthreads();
    if (tid < 10) {
        float mx = logits[0];
        for (int i = 1; i < 10; i++) mx = fmaxf(mx, logits[i]);
        float sum = 0.f;
        for (int i = 0; i < 10; i++) sum += expf(logits[i] - mx);
        out[b * 10 + tid] = expf(logits[tid] - mx) / sum;
    }
}

// ---------------------------------------------------------------------------
extern "C" void kernel_launch(void* const* d_in, const int* in_sizes, int n_in,
                              void* d_out, int out_size, void* d_ws, size_t ws_size,
                              hipStream_t stream)
{
    const float* x      = (const float*)d_in[0];
    const float* w11    = (const float*)d_in[1];
    const float* b11    = (const float*)d_in[2];
    const float* g11    = (const float*)d_in[3];
    const float* be11   = (const float*)d_in[4];
    const float* woff12 = (const float*)d_in[5];
    const float* w12    = (const float*)d_in[6];
    const float* b12    = (const float*)d_in[7];
    const float* g12    = (const float*)d_in[8];
    const float* be12   = (const float*)d_in[9];
    const float* woff21 = (const float*)d_in[10];
    const float* w21    = (const float*)d_in[11];
    const float* b21    = (const float*)d_in[12];
    const float* g21    = (const float*)d_in[13];
    const float* be21   = (const float*)d_in[14];
    const float* woff22 = (const float*)d_in[15];
    const float* w22    = (const float*)d_in[16];
    const float* b22    = (const float*)d_in[17];
    const float* g22    = (const float*)d_in[18];
    const float* be22   = (const float*)d_in[19];
    const float* wfc    = (const float*)d_in[20];
    const float* bfc    = (const float*)d_in[21];
    float* out = (float*)d_out;

    float* ws    = (float*)d_ws;
    const size_t SZ_B = 25690112;   // 64*32*112*112 = 64*128*56*56 floats
    float* Bbuf  = ws;
    float* Cbuf  = Bbuf + SZ_B;
    float* stats = Cbuf + SZ_B;      // 512
    float* aff   = stats + 512;      // 512
    float* poolb = aff + 512;        // 8192
    ushort_t* warena = (ushort_t*)(poolb + 8192);
    const size_t W12 = 9 * 64 * 32;
    const size_t W21 = 9 * 128 * 64;
    const size_t W22 = 9 * 256 * 128;
    ushort_t* wp12h = warena;          ushort_t* wp12l = wp12h + W12;
    ushort_t* wp21h = wp12l + W12;     ushort_t* wp21l = wp21h + W21;
    ushort_t* wc21h = wp21l + W21;     ushort_t* wc21l = wc21h + W21;
    ushort_t* wp22h = wc21l + W21;     ushort_t* wp22l = wp22h + W22;

    const int B = 64;

    prep_w_kernel<<<(9 * 64 * 32 + 255) / 256, 256, 0, stream>>>(woff12, wp12h, wp12l, 64, 32);
    prep_w_kernel<<<(9 * 128 * 64 + 255) / 256, 256, 0, stream>>>(woff21, wp21h, wp21l, 128, 64);
    prep_w_kernel<<<(9 * 128 * 64 + 255) / 256, 256, 0, stream>>>(w21, wc21h, wc21l, 128, 64);
    prep_w_kernel<<<(9 * 256 * 128 + 255) / 256, 256, 0, stream>>>(woff22, wp22h, wp22l, 256, 128);

    // ---- Layer 1.1: conv(1->32, s1)+relu -> Bbuf raw; stats; finalize ----
    conv3x3_kernel<1><<<dim3(4, 4, B * (32 / 8)), 256, 0, stream>>>(
        x, w11, b11, Bbuf, B, 1, 112, 112, 32, 112, 112, 1);
    zero_kernel<<<2, 256, 0, stream>>>(stats, 512);
    bn_stats_kernel<<<dim3(32, 64), 256, 0, stream>>>(Bbuf, stats, B, 32, 12544);
    bn_finalize_kernel<<<1, 256, 0, stream>>>(stats, g11, be11, 1.f / (64.f * 12544.f), aff, 32);

    // ---- deform12 (MFMA, single-buf): BN(1.1)-fused offconv + resample ----
    mfma_conv_kernel<112, 112, 32, 64, 2, true, true, false, false>
        <<<dim3(196, B, 1), 128, 0, stream>>>(Bbuf, wp12h, wp12l, aff, nullptr, Cbuf);

    // ---- Layer 1.2: conv(32->64, s2)+relu -> Bbuf raw; stats; finalize ----
    conv3x3_kernel<2><<<dim3(2, 2, B * (64 / 8)), 256, 0, stream>>>(
        Cbuf, w12, b12, Bbuf, B, 32, 112, 112, 64, 56, 56, 1);
    zero_kernel<<<2, 256, 0, stream>>>(stats, 512);
    bn_stats_kernel<<<dim3(64, 64), 256, 0, stream>>>(Bbuf, stats, B, 64, 3136);
    bn_finalize_kernel<<<1, 256, 0, stream>>>(stats, g12, be12, 1.f / (64.f * 3136.f), aff, 64);

    // ---- deform21 (MFMA, dbuf): BN(1.2)-fused offconv + resample ----
    mfma_conv_kernel<56, 56, 64, 128, 4, true, true, false, true>
        <<<dim3(49, B, 1), 128, 0, stream>>>(Bbuf, wp21h, wp21l, aff, nullptr, Cbuf);

    // ---- Layer 2.1 (MFMA, dbuf): conv(64->128, s1)+bias+relu -> Bbuf ----
    mfma_conv_kernel<56, 56, 64, 128, 4, false, false, true, true>
        <<<dim3(49, B, 1), 128, 0, stream>>>(Cbuf, wc21h, wc21l, nullptr, b21, Bbuf);
    zero_kernel<<<2, 256, 0, stream>>>(stats, 512);
    bn_stats_kernel<<<dim3(128, 64), 256, 0, stream>>>(Bbuf, stats, B, 128, 3136);
    bn_finalize_kernel<<<1, 256, 0, stream>>>(stats, g21, be21, 1.f / (64.f * 3136.f), aff, 128);

    // ---- deform22 (MFMA, dbuf): BN(2.1)-fused offconv + resample ----
    mfma_conv_kernel<56, 56, 128, 256, 4, true, true, false, true>
        <<<dim3(49, B, 2), 128, 0, stream>>>(Bbuf, wp22h, wp22l, aff, nullptr, Cbuf);

    // ---- Layer 2.2: conv(128->128, s2)+relu -> Bbuf raw; stats ----
    conv3x3_kernel<2><<<dim3(1, 1, B * (128 / 8)), 256, 0, stream>>>(
        Cbuf, w22, b22, Bbuf, B, 128, 56, 56, 128, 28, 28, 1);
    zero_kernel<<<2, 256, 0, stream>>>(stats, 512);
    bn_stats_kernel<<<dim3(128, 64), 256, 0, stream>>>(Bbuf, stats, B, 128, 784);

    // ---- Pool (BN(2.2) fused) + FC + softmax ----
    pool_kernel<<<B * 128, 256, 0, stream>>>(
        Bbuf, stats, g22, be22, 1.f / (64.f * 784.f), poolb, 128, 784);
    fc_softmax_kernel<<<B, 128, 0, stream>>>(poolb, wfc, bfc, out);
}

// Round 10
// 2056.379 us; speedup vs baseline: 7.5190x; 1.8534x over previous
//
#include <hip/hip_runtime.h>
#include <math.h>

#define BN_EPS 1e-5f

typedef unsigned short ushort_t;
typedef __attribute__((ext_vector_type(8))) short short8;     // 8 bf16 (4 VGPR)
typedef __attribute__((ext_vector_type(16))) float floatx16;  // MFMA 32x32 acc

// Split fp32 into bf16 hi (bit-truncate, exact) + bf16 lo (truncated remainder).
__device__ __forceinline__ void split_bf16(float v, ushort_t& h, ushort_t& l) {
    unsigned u = __float_as_uint(v);
    float fhi = __uint_as_float(u & 0xFFFF0000u);
    h = (ushort_t)(u >> 16);
    l = (ushort_t)(__float_as_uint(v - fhi) >> 16);
}

// ---------------------------------------------------------------------------
// Weight prep: OIHW fp32 -> tiled [tap][o>>5][i>>3][o&31][i&7] bf16 hi/lo.
// ---------------------------------------------------------------------------
__global__ __launch_bounds__(256) void prep_w_kernel(
    const float* __restrict__ w, ushort_t* __restrict__ hi,
    ushort_t* __restrict__ lo, int O, int I)
{
    int idx = blockIdx.x * 256 + threadIdx.x;
    int n = 9 * O * I;
    if (idx >= n) return;
    int i = idx % I;
    int rest = idx / I;
    int o = rest % O;
    int t = rest / O;
    float v = w[((size_t)o * I + i) * 9 + t];
    size_t d = ((((size_t)t * (O / 32) + (o >> 5)) * (I / 8) + (i >> 3)) * 32
                + (o & 31)) * 8 + (i & 7);
    split_bf16(v, hi[d], lo[d]);
}

// ---------------------------------------------------------------------------
// A prep (per layer): NCHW fp32 (+optional BN affine) -> tiled
// [b][p>>5][ci>>3][p&31][ci&7] bf16 hi/lo.
// ---------------------------------------------------------------------------
template<bool BNIN>
__global__ __launch_bounds__(256) void pack_a_kernel(
    const float* __restrict__ x, const float* __restrict__ aff,
    ushort_t* __restrict__ xh, ushort_t* __restrict__ xl,
    int C, int HW, int total)
{
    int idx = blockIdx.x * 256 + threadIdx.x;
    if (idx >= total) return;
    int p = idx % HW;
    int rest = idx / HW;
    int cg = rest % (C / 8);
    int b  = rest / (C / 8);
    const float* xp = x + ((size_t)b * C + cg * 8) * HW + p;
    short8 hv, lv;
    #pragma unroll
    for (int j = 0; j < 8; j++) {
        float v = xp[(size_t)j * HW];
        if (BNIN) {
            int c = cg * 8 + j;
            v = fmaf(v, aff[2 * c], aff[2 * c + 1]);
        }
        ushort_t h, l;
        split_bf16(v, h, l);
        hv[j] = (short)h; lv[j] = (short)l;
    }
    size_t base = (size_t)b * C * HW + ((size_t)(p >> 5) * (C / 8) + cg) * 256
                + (size_t)(p & 31) * 8;
    *(short8*)(xh + base) = hv;
    *(short8*)(xl + base) = lv;
}

// ---------------------------------------------------------------------------
__global__ void bn_finalize_kernel(
    const float* __restrict__ stats, const float* __restrict__ g,
    const float* __restrict__ be, float inv_cnt, float* __restrict__ aff, int C)
{
    int c = threadIdx.x;
    if (c < C) {
        float m  = stats[c] * inv_cnt;
        float vv = stats[C + c] * inv_cnt - m * m;
        float sc = g[c] / sqrtf(vv + BN_EPS);
        aff[2 * c]     = sc;
        aff[2 * c + 1] = be[c] - m * sc;
    }
}

// ---------------------------------------------------------------------------
// Barrier-free, LDS-free MFMA 3x3 conv (split-bf16 fp32 emulation:
// Ah*Bh + Ah*Bl + Al*Bh). A and (for DEFORM) the bilinear gather source come
// from the pre-packed tiled xt (BN already applied by pack); B from tiled
// weights. The kernel never reads the fp32 buffer -> the fp32 activation
// arena can be a SINGLE buffer F with in-place write-back (ws budget 208 MB,
// the proven round-8 envelope; round 9's 311 MB overflowed ws -> crash).
// No __syncthreads anywhere. Block = 128 thr (2 waves); wave = 32-output-
// pixel M-tile x NT 32-ch N-tiles. Grid (ceil(HWo/64), B, CO/(NT*32)).
// Epilogues (verified exact rounds 3-8): DEFORM pair-in-lane remap, gather
// reconstructs hi+lo (~2^-17 rel err); BREL bias+relu store (p<HWo masked).
// ---------------------------------------------------------------------------
template<int S, int W, int H, int CIN, int CO, int NT, bool DEFORM, bool BREL>
__global__ __launch_bounds__(128, 2) void mfma_conv_g(
    const ushort_t* __restrict__ xh, const ushort_t* __restrict__ xl,
    const ushort_t* __restrict__ wh, const ushort_t* __restrict__ wl,
    const float* __restrict__ bias, float* __restrict__ out)
{
    constexpr int Wo  = W / S, Ho = H / S;
    constexpr int HWo = Wo * Ho;
    constexpr int HWi = W * H;
    constexpr int KB  = CIN / 8;            // k-groups of 8
    const short8 zero8 = {0, 0, 0, 0, 0, 0, 0, 0};

    const int tid  = threadIdx.x;
    const int wv   = tid >> 6;
    const int lane = tid & 63;
    const int l31  = lane & 31;
    const int kg   = lane >> 5;
    const int p0   = blockIdx.x * 64;
    const int b    = blockIdx.y;
    const int n0t  = blockIdx.z * NT;       // n-tile base (co>>5 units)

    const int mp  = p0 + wv * 32 + l31;     // output pixel of this lane
    const int mpc = mp < HWo ? mp : HWo - 1;
    const int py  = mpc / Wo, px = mpc % Wo;

    const size_t xtb = (size_t)b * CIN * HWi;   // ushort offset of image

    // per-tap A offsets (ushort units) + validity
    unsigned aoff[9];
    int avalid[9];
    #pragma unroll
    for (int ki = 0; ki < 3; ki++) {
        #pragma unroll
        for (int kj = 0; kj < 3; kj++) {
            int t  = ki * 3 + kj;
            int iy = py * S + ki - 1, ix = px * S + kj - 1;
            bool v = (iy >= 0 && iy < H && ix >= 0 && ix < W);
            int ps = v ? iy * W + ix : 0;
            aoff[t]   = (unsigned)((ps >> 5) * KB * 256 + (ps & 31) * 8);
            avalid[t] = v;
        }
    }

    floatx16 acc[NT];
    #pragma unroll
    for (int nt = 0; nt < NT; nt++)
        #pragma unroll
        for (int i = 0; i < 16; i++) acc[nt][i] = 0.f;

    for (int c2 = 0; c2 < CIN / 16; c2++) {
        const unsigned kb = c2 * 2 + kg;
        #pragma unroll
        for (int t = 0; t < 9; t++) {
            const size_t au = xtb + aoff[t] + (size_t)kb * 256;
            short8 ah = *(const short8*)(xh + au);
            short8 al = *(const short8*)(xl + au);
            if (!avalid[t]) { ah = zero8; al = zero8; }
            #pragma unroll
            for (int nt = 0; nt < NT; nt++) {
                const size_t bofs =
                    ((((size_t)t * (CO / 32) + (n0t + nt)) * KB + kb) * 32 + l31) * 8;
                short8 bh = *(const short8*)(wh + bofs);
                short8 bl = *(const short8*)(wl + bofs);
                acc[nt] = __builtin_amdgcn_mfma_f32_32x32x16_bf16(ah, bh, acc[nt], 0, 0, 0);
                acc[nt] = __builtin_amdgcn_mfma_f32_32x32x16_bf16(ah, bl, acc[nt], 0, 0, 0);
                acc[nt] = __builtin_amdgcn_mfma_f32_32x32x16_bf16(al, bh, acc[nt], 0, 0, 0);
            }
        }
    }

    if (DEFORM) {
        #pragma unroll
        for (int nt = 0; nt < NT; nt++) {
            int gch  = (n0t + nt) * 32 + l31;   // conv channel
            int c    = gch >> 1, half = gch & 1;
            const size_t cbase = xtb + (size_t)(c >> 3) * 256 + (c & 7);
            #pragma unroll
            for (int t = 0; t < 8; t++) {
                int reg0 = 2 * t;
                int row  = (reg0 & 3) + 8 * (reg0 >> 2) + 4 * kg;
                int p    = p0 + wv * 32 + row;  // even conv pixel
                float oi = acc[nt][reg0];
                float oj = acc[nt][reg0 + 1];
                int q  = half * (HWi >> 1) + (p >> 1);
                int qi = q / W, qj = q % W;
                float ci_ = fminf(fmaxf(oi + (float)qi, 0.f), (float)(H - 1));
                float cj_ = fminf(fmaxf(oj + (float)qj, 0.f), (float)(W - 1));
                float i0f = floorf(ci_), j0f = floorf(cj_);
                int i0 = (int)i0f, i1 = (int)ceilf(ci_);
                int j0 = (int)j0f, j1 = (int)ceilf(cj_);
                auto ld = [&](int iy, int jx) -> float {
                    int ps = iy * W + jx;
                    size_t idx = cbase + ((size_t)(ps >> 5) * KB) * 256
                               + (size_t)(ps & 31) * 8;
                    return __uint_as_float((unsigned)xh[idx] << 16)
                         + __uint_as_float((unsigned)xl[idx] << 16);
                };
                float v00 = ld(i0, j0);
                float v10 = ld(i1, j0);
                float v01 = ld(i0, j1);
                float v11 = ld(i1, j1);
                float di = ci_ - i0f, dj = cj_ - j0f;
                float top = v00 + di * (v10 - v00);
                float bot = v01 + di * (v11 - v01);
                out[((size_t)b * CIN + c) * HWi + q] = top + dj * (bot - top);
            }
        }
    }
    if (BREL) {
        #pragma unroll
        for (int nt = 0; nt < NT; nt++) {
            int co = (n0t + nt) * 32 + l31;
            float bv = bias[co];
            #pragma unroll
            for (int reg = 0; reg < 16; reg++) {
                int row = (reg & 3) + 8 * (reg >> 2) + 4 * kg;
                int p   = p0 + wv * 32 + row;
                if (p < HWo)
                    out[((size_t)b * CO + co) * HWo + p] = fmaxf(acc[nt][reg] + bv, 0.f);
            }
        }
    }
}

// ---------------------------------------------------------------------------
// Vector direct 3x3 conv (kept only for conv11: Cin=1).
// ---------------------------------------------------------------------------
template<int STRIDE>
__global__ __launch_bounds__(256) void conv3x3_kernel(
    const float* __restrict__ in, const float* __restrict__ wgt,
    const float* __restrict__ bias, float* __restrict__ out,
    int B, int Cin, int H, int W, int Cout, int Ho, int Wo, int do_relu)
{
    constexpr int TILE = 28;
    constexpr int PR   = (TILE - 1) * STRIDE + 3;
    constexpr int PADW = (STRIDE == 1) ? 32 : 60;
    constexpr int COPB = 8;
    constexpr int RW   = STRIDE + 3;
    __shared__ float patch[PR * PADW];

    int cpg  = Cout / COPB;
    int bz   = blockIdx.z;
    int cog  = bz % cpg;
    int b    = bz / cpg;
    int co0  = cog * COPB;
    int tid  = threadIdx.x;
    int oy0  = blockIdx.y * TILE, ox0 = blockIdx.x * TILE;
    int iy0  = oy0 * STRIDE - 1,  ix0 = ox0 * STRIDE - 1;

    bool active = tid < 196;
    int ty = tid / 14, tx = tid % 14;
    int py = oy0 + 2 * ty, px = ox0 + 2 * tx;

    float acc[COPB][4];
    #pragma unroll
    for (int i = 0; i < COPB; i++) {
        float bv = bias ? bias[co0 + i] : 0.f;
        #pragma unroll
        for (int j = 0; j < 4; j++) acc[i][j] = bv;
    }

    const size_t HW = (size_t)H * W;
    for (int ci = 0; ci < Cin; ci++) {
        const float* ip = in + ((size_t)b * Cin + ci) * HW;
        for (int t = tid; t < PR * PADW; t += 256) {
            int sy = t / PADW, sx = t % PADW;
            float v = 0.f;
            int gy = iy0 + sy, gx = ix0 + sx;
            if (sx < PR && gy >= 0 && gy < H && gx >= 0 && gx < W)
                v = ip[(size_t)gy * W + gx];
            patch[t] = v;
        }
        __syncthreads();
        if (active) {
            float r[RW][RW];
            #pragma unroll
            for (int rr = 0; rr < RW; rr++) {
                int rowbase = (2 * ty * STRIDE + rr) * PADW + 2 * tx * STRIDE;
                if (STRIDE == 1) {
                    float2 a = *(const float2*)&patch[rowbase];
                    float2 c = *(const float2*)&patch[rowbase + 2];
                    r[rr][0] = a.x; r[rr][1] = a.y; r[rr][2] = c.x; r[rr][3] = c.y;
                } else {
                    float4 a = *(const float4*)&patch[rowbase];
                    r[rr][0] = a.x; r[rr][1] = a.y; r[rr][2] = a.z; r[rr][3] = a.w;
                    r[rr][4] = patch[rowbase + 4];
                }
            }
            const float* wb = wgt + ((size_t)co0 * Cin + ci) * 9;
            #pragma unroll
            for (int i = 0; i < COPB; i++) {
                const float* wp = wb + (size_t)i * Cin * 9;
                #pragma unroll
                for (int ki = 0; ki < 3; ki++)
                    #pragma unroll
                    for (int kj = 0; kj < 3; kj++) {
                        float w = wp[ki * 3 + kj];
                        acc[i][0] = fmaf(r[ki][kj],                   w, acc[i][0]);
                        acc[i][1] = fmaf(r[ki][kj + STRIDE],          w, acc[i][1]);
                        acc[i][2] = fmaf(r[ki + STRIDE][kj],          w, acc[i][2]);
                        acc[i][3] = fmaf(r[ki + STRIDE][kj + STRIDE], w, acc[i][3]);
                    }
            }
        }
        __syncthreads();
    }
    if (active) {
        #pragma unroll
        for (int rr = 0; rr < 2; rr++) {
            #pragma unroll
            for (int cc = 0; cc < 2; cc++) {
                int oy = py + rr, ox = px + cc;
                if (oy < Ho && ox < Wo) {
                    #pragma unroll
                    for (int i = 0; i < COPB; i++) {
                        float v = acc[i][rr * 2 + cc];
                        if (do_relu) v = fmaxf(v, 0.f);
                        out[(((size_t)b * Cout + co0 + i) * Ho + oy) * Wo + ox] = v;
                    }
                }
            }
        }
    }
}

// ---------------------------------------------------------------------------
__global__ __launch_bounds__(256) void bn_stats_kernel(
    const float* __restrict__ x, float* __restrict__ stats,
    int B, int C, int HW)
{
    int c = blockIdx.x;
    long long cnt = (long long)B * HW;
    long long step = (long long)gridDim.y * blockDim.x;
    float s = 0.f, s2 = 0.f;
    for (long long t = (long long)blockIdx.y * blockDim.x + threadIdx.x; t < cnt; t += step) {
        int b  = (int)(t / HW);
        int sp = (int)(t % HW);
        float v = x[((size_t)b * C + c) * (size_t)HW + sp];
        s += v; s2 += v * v;
    }
    for (int off = 32; off; off >>= 1) {
        s  += __shfl_down(s, off);
        s2 += __shfl_down(s2, off);
    }
    __shared__ float ls[4], ls2[4];
    int wave = threadIdx.x >> 6, lane = threadIdx.x & 63;
    if (lane == 0) { ls[wave] = s; ls2[wave] = s2; }
    __syncthreads();
    if (threadIdx.x == 0) {
        float ts = 0.f, ts2 = 0.f;
        for (int i = 0; i < 4; i++) { ts += ls[i]; ts2 += ls2[i]; }
        atomicAdd(&stats[c], ts);
        atomicAdd(&stats[C + c], ts2);
    }
}

// ---------------------------------------------------------------------------
__global__ void zero_kernel(float* __restrict__ p, int n)
{
    int i = blockIdx.x * blockDim.x + threadIdx.x;
    if (i < n) p[i] = 0.f;
}

// ---------------------------------------------------------------------------
__global__ __launch_bounds__(256) void pool_kernel(
    const float* __restrict__ x, const float* __restrict__ stats,
    const float* __restrict__ g, const float* __restrict__ be,
    float inv_cnt, float* __restrict__ out, int C, int HW)
{
    int bc = blockIdx.x;
    int c  = bc % C;
    const float* xp = x + (size_t)bc * HW;
    float s = 0.f;
    for (int i = threadIdx.x; i < HW; i += blockDim.x) s += xp[i];
    for (int off = 32; off; off >>= 1) s += __shfl_down(s, off);
    __shared__ float ls[4];
    int wave = threadIdx.x >> 6, lane = threadIdx.x & 63;
    if (lane == 0) ls[wave] = s;
    __syncthreads();
    if (threadIdx.x == 0) {
        float t = 0.f;
        for (int i = 0; i < 4; i++) t += ls[i];
        float mean = t / (float)HW;
        float m  = stats[c] * inv_cnt;
        float vv = stats[C + c] * inv_cnt - m * m;
        float sc = g[c] / sqrtf(vv + BN_EPS);
        float sh = be[c] - m * sc;
        out[bc] = mean * sc + sh;
    }
}

// ---------------------------------------------------------------------------
__global__ __launch_bounds__(128) void fc_softmax_kernel(
    const float* __restrict__ pool, const float* __restrict__ wfc,
    const float* __restrict__ bfc, float* __restrict__ out)
{
    int b = blockIdx.x;
    __shared__ float row[128];
    __shared__ float logits[10];
    int tid = threadIdx.x;
    row[tid] = pool[b * 128 + tid];
    __syncthreads();
    if (tid < 10) {
        float s = bfc[tid];
        for (int k = 0; k < 128; k++) s = fmaf(row[k], wfc[tid * 128 + k], s);
        logits[tid] = s;
    }
    __syncthreads();
    if (tid < 10) {
        float mx = logits[0];
        for (int i = 1; i < 10; i++) mx = fmaxf(mx, logits[i]);
        float sum = 0.f;
        for (int i = 0; i < 10; i++) sum += expf(logits[i] - mx);
        out[b * 10 + tid] = expf(logits[tid] - mx) / sum;
    }
}

// ---------------------------------------------------------------------------
extern "C" void kernel_launch(void* const* d_in, const int* in_sizes, int n_in,
                              void* d_out, int out_size, void* d_ws, size_t ws_size,
                              hipStream_t stream)
{
    const float* x      = (const float*)d_in[0];
    const float* w11    = (const float*)d_in[1];
    const float* b11    = (const float*)d_in[2];
    const float* g11    = (const float*)d_in[3];
    const float* be11   = (const float*)d_in[4];
    const float* woff12 = (const float*)d_in[5];
    const float* w12    = (const float*)d_in[6];
    const float* b12    = (const float*)d_in[7];
    const float* g12    = (const float*)d_in[8];
    const float* be12   = (const float*)d_in[9];
    const float* woff21 = (const float*)d_in[10];
    const float* w21    = (const float*)d_in[11];
    const float* b21    = (const float*)d_in[12];
    const float* g21    = (const float*)d_in[13];
    const float* be21   = (const float*)d_in[14];
    const float* woff22 = (const float*)d_in[15];
    const float* w22    = (const float*)d_in[16];
    const float* b22    = (const float*)d_in[17];
    const float* g22    = (const float*)d_in[18];
    const float* be22   = (const float*)d_in[19];
    const float* wfc    = (const float*)d_in[20];
    const float* bfc    = (const float*)d_in[21];
    float* out = (float*)d_out;

    // Arena: ONE fp32 activation buffer F (102.8 MB) + packed xt hi/lo
    // (51.4 MB each) + stats/aff/pool + tiled bf16 weights (2.5 MB).
    // Total 208,064,512 B — same envelope as the passing round-8 run.
    // MFMA kernels read only xt+weights, so in-place write-back into F after
    // pack is hazard-free.
    float* ws    = (float*)d_ws;
    const size_t SZ_B = 25690112;   // 64*32*112*112 = 64*128*56*56 elements
    float* F     = ws;
    float* stats = F + SZ_B;         // 512
    float* aff   = stats + 512;      // 512
    float* poolb = aff + 512;        // 8192
    ushort_t* xth = (ushort_t*)(poolb + 8192);
    ushort_t* xtl = xth + SZ_B;      // SZ_B ushorts each
    ushort_t* warena = xtl + SZ_B;
    const size_t W12 = 9 * 64 * 32;     // 18432  (offconv12 / conv12)
    const size_t W21 = 9 * 128 * 64;    // 73728  (offconv21 / conv21)
    const size_t W22o = 9 * 256 * 128;  // 294912 (offconv22)
    const size_t W22c = 9 * 128 * 128;  // 147456 (conv22)
    ushort_t* wp12h = warena;          ushort_t* wp12l = wp12h + W12;
    ushort_t* wc12h = wp12l + W12;     ushort_t* wc12l = wc12h + W12;
    ushort_t* wp21h = wc12l + W12;     ushort_t* wp21l = wp21h + W21;
    ushort_t* wc21h = wp21l + W21;     ushort_t* wc21l = wc21h + W21;
    ushort_t* wp22h = wc21l + W21;     ushort_t* wp22l = wp22h + W22o;
    ushort_t* wc22h = wp22l + W22o;    ushort_t* wc22l = wc22h + W22c;

    const int B = 64;

    // ---- weight prep (tiled bf16 hi/lo) ----
    prep_w_kernel<<<(9*64*32   + 255)/256, 256, 0, stream>>>(woff12, wp12h, wp12l, 64, 32);
    prep_w_kernel<<<(9*64*32   + 255)/256, 256, 0, stream>>>(w12,    wc12h, wc12l, 64, 32);
    prep_w_kernel<<<(9*128*64  + 255)/256, 256, 0, stream>>>(woff21, wp21h, wp21l, 128, 64);
    prep_w_kernel<<<(9*128*64  + 255)/256, 256, 0, stream>>>(w21,    wc21h, wc21l, 128, 64);
    prep_w_kernel<<<(9*256*128 + 255)/256, 256, 0, stream>>>(woff22, wp22h, wp22l, 256, 128);
    prep_w_kernel<<<(9*128*128 + 255)/256, 256, 0, stream>>>(w22,    wc22h, wc22l, 128, 128);

    // ---- Layer 1.1: conv(1->32, s1)+relu -> F raw; stats; finalize ----
    conv3x3_kernel<1><<<dim3(4, 4, B * (32 / 8)), 256, 0, stream>>>(
        x, w11, b11, F, B, 1, 112, 112, 32, 112, 112, 1);
    zero_kernel<<<2, 256, 0, stream>>>(stats, 512);
    bn_stats_kernel<<<dim3(32, 64), 256, 0, stream>>>(F, stats, B, 32, 12544);
    bn_finalize_kernel<<<1, 256, 0, stream>>>(stats, g11, be11, 1.f/(64.f*12544.f), aff, 32);

    // ---- deform12: pack BN(1.1) F -> xt; MFMA offconv+resample -> F ----
    pack_a_kernel<true><<<(B*4*12544 + 255)/256, 256, 0, stream>>>(
        F, aff, xth, xtl, 32, 12544, B*4*12544);
    mfma_conv_g<1, 112, 112, 32, 64, 2, true, false>
        <<<dim3(196, B, 1), 128, 0, stream>>>(xth, xtl, wp12h, wp12l, nullptr, F);

    // ---- Layer 1.2 (MFMA s2): pack F -> xt; conv+bias+relu -> F ----
    pack_a_kernel<false><<<(B*4*12544 + 255)/256, 256, 0, stream>>>(
        F, nullptr, xth, xtl, 32, 12544, B*4*12544);
    mfma_conv_g<2, 112, 112, 32, 64, 2, false, true>
        <<<dim3(49, B, 1), 128, 0, stream>>>(xth, xtl, wc12h, wc12l, b12, F);
    zero_kernel<<<2, 256, 0, stream>>>(stats, 512);
    bn_stats_kernel<<<dim3(64, 64), 256, 0, stream>>>(F, stats, B, 64, 3136);
    bn_finalize_kernel<<<1, 256, 0, stream>>>(stats, g12, be12, 1.f/(64.f*3136.f), aff, 64);

    // ---- deform21: pack BN(1.2) F -> xt; MFMA offconv+resample -> F ----
    pack_a_kernel<true><<<(B*8*3136 + 255)/256, 256, 0, stream>>>(
        F, aff, xth, xtl, 64, 3136, B*8*3136);
    mfma_conv_g<1, 56, 56, 64, 128, 4, true, false>
        <<<dim3(49, B, 1), 128, 0, stream>>>(xth, xtl, wp21h, wp21l, nullptr, F);

    // ---- Layer 2.1 (MFMA s1): pack F -> xt; conv+bias+relu -> F ----
    pack_a_kernel<false><<<(B*8*3136 + 255)/256, 256, 0, stream>>>(
        F, nullptr, xth, xtl, 64, 3136, B*8*3136);
    mfma_conv_g<1, 56, 56, 64, 128, 4, false, true>
        <<<dim3(49, B, 1), 128, 0, stream>>>(xth, xtl, wc21h, wc21l, b21, F);
    zero_kernel<<<2, 256, 0, stream>>>(stats, 512);
    bn_stats_kernel<<<dim3(128, 64), 256, 0, stream>>>(F, stats, B, 128, 3136);
    bn_finalize_kernel<<<1, 256, 0, stream>>>(stats, g21, be21, 1.f/(64.f*3136.f), aff, 128);

    // ---- deform22: pack BN(2.1) F -> xt; MFMA offconv+resample -> F ----
    pack_a_kernel<true><<<(B*16*3136 + 255)/256, 256, 0, stream>>>(
        F, aff, xth, xtl, 128, 3136, B*16*3136);
    mfma_conv_g<1, 56, 56, 128, 256, 4, true, false>
        <<<dim3(49, B, 2), 128, 0, stream>>>(xth, xtl, wp22h, wp22l, nullptr, F);

    // ---- Layer 2.2 (MFMA s2): pack F -> xt; conv+bias+relu -> F ----
    pack_a_kernel<false><<<(B*16*3136 + 255)/256, 256, 0, stream>>>(
        F, nullptr, xth, xtl, 128, 3136, B*16*3136);
    mfma_conv_g<2, 56, 56, 128, 128, 4, false, true>
        <<<dim3(13, B, 1), 128, 0, stream>>>(xth, xtl, wc22h, wc22l, b22, F);
    zero_kernel<<<2, 256, 0, stream>>>(stats, 512);
    bn_stats_kernel<<<dim3(128, 64), 256, 0, stream>>>(F, stats, B, 128, 784);

    // ---- Pool (BN(2.2) fused) + FC + softmax ----
    pool_kernel<<<B * 128, 256, 0, stream>>>(
        F, stats, g22, be22, 1.f/(64.f*784.f), poolb, 128, 784);
    fc_softmax_kernel<<<B, 128, 0, stream>>>(poolb, wfc, bfc, out);
}